// Round 1
// baseline (1926.460 us; speedup 1.0000x reference)
//
#include <hip/hip_runtime.h>
#include <cstddef>

static constexpr int NN = 50000;
static constexpr int NE = 600000;

// ---------------- degree / norm ----------------
__global__ __launch_bounds__(256)
void count_deg_k(const int* __restrict__ dstv, int* __restrict__ deg) {
    int e = blockIdx.x * 256 + threadIdx.x;
    if (e < NE) atomicAdd(&deg[dstv[e]], 1);
}

__global__ __launch_bounds__(256)
void dinv_k(const int* __restrict__ deg, float* __restrict__ dinv) {
    int i = blockIdx.x * 256 + threadIdx.x;
    if (i < NN) dinv[i] = rsqrtf((float)deg[i] + 1.0f);  // +1 self-loop
}

// ---------------- fused dual GEMM ----------------
// Computes outA = X @ Wa  and  outB = X @ Wb (+ biasB), both K x OC row-major
// weights. One 32-channel chunk per blockIdx.y; 64 nodes per blockIdx.x.
// Thread tile: 4 consecutive channels, float4 loads of X row, W chunk in LDS.
template<int K>
__global__ __launch_bounds__(256)
void gemm_dual(const float* __restrict__ X,
               const float* __restrict__ Wa,
               const float* __restrict__ Wb,
               const float* __restrict__ biasB,
               float* __restrict__ outA,
               float* __restrict__ outB,
               int OC, int ostride)
{
    __shared__ float Ws[K * 32];
    const int nchunk = OC >> 5;
    const int chunk  = blockIdx.y;
    const int mat    = chunk / nchunk;            // 0 = Wa, 1 = Wb
    const int c0     = (chunk % nchunk) << 5;
    const float* __restrict__ W = mat ? Wb : Wa;
    for (int i = threadIdx.x; i < K * 32; i += 256) {
        int k = i >> 5, cl = i & 31;
        Ws[i] = W[k * OC + c0 + cl];
    }
    __syncthreads();

    const int nl  = threadIdx.x >> 3;             // 0..31 node lane
    const int cl4 = (threadIdx.x & 7) << 2;       // channel*4 within chunk

    float bx = 0.f, by = 0.f, bz = 0.f, bw = 0.f;
    if (mat && biasB) {
        bx = biasB[c0 + cl4 + 0];
        by = biasB[c0 + cl4 + 1];
        bz = biasB[c0 + cl4 + 2];
        bw = biasB[c0 + cl4 + 3];
    }
    float* __restrict__ outp = mat ? outB : outA;

    for (int ni = 0; ni < 2; ++ni) {
        int node = blockIdx.x * 64 + ni * 32 + nl;
        if (node >= NN) break;
        const float4* __restrict__ xr = (const float4*)(X + (size_t)node * K);
        float ax = bx, ay = by, az = bz, aw = bw;
        #pragma unroll 4
        for (int k4 = 0; k4 < K / 4; ++k4) {
            float4 xv = xr[k4];
            float xk[4] = {xv.x, xv.y, xv.z, xv.w};
            #pragma unroll
            for (int j = 0; j < 4; ++j) {
                const float4 wv = *(const float4*)&Ws[((k4 << 2) + j) * 32 + cl4];
                ax = fmaf(xk[j], wv.x, ax);
                ay = fmaf(xk[j], wv.y, ay);
                az = fmaf(xk[j], wv.z, az);
                aw = fmaf(xk[j], wv.w, aw);
            }
        }
        float4 r = {ax, ay, az, aw};
        *(float4*)&outp[(size_t)node * ostride + c0 + cl4] = r;
    }
}

// ---------------- edge scatter-add (atomic) ----------------
template<int OC>
__global__ __launch_bounds__(256)
void scatter_add_k(const int* __restrict__ srcv,
                   const int* __restrict__ dstv,
                   const float* __restrict__ msg,
                   float* __restrict__ acc)
{
    constexpr int CP = OC / 4;
    int idx = blockIdx.x * 256 + threadIdx.x;
    if (idx >= NE * CP) return;
    int e  = idx / CP;
    int c4 = (idx % CP) << 2;
    int s = srcv[e], d = dstv[e];
    const float4 v = *(const float4*)&msg[(size_t)s * OC + c4];
    float* a = acc + (size_t)d * OC + c4;
    atomicAdd(a + 0, v.x);
    atomicAdd(a + 1, v.y);
    atomicAdd(a + 2, v.z);
    atomicAdd(a + 3, v.w);
}

// ---------------- elementwise ----------------
__global__ __launch_bounds__(256)
void relu_k(float4* __restrict__ p, int n4) {
    int i = blockIdx.x * 256 + threadIdx.x;
    if (i >= n4) return;
    float4 v = p[i];
    v.x = fmaxf(v.x, 0.f); v.y = fmaxf(v.y, 0.f);
    v.z = fmaxf(v.z, 0.f); v.w = fmaxf(v.w, 0.f);
    p[i] = v;
}

// y *= dinv[i]  (in place), Z = y  (self-loop init). 64 ch per node -> 16 float4.
__global__ __launch_bounds__(256)
void scale_init_k(float* __restrict__ y, const float* __restrict__ dinv,
                  float* __restrict__ Z)
{
    int idx = blockIdx.x * 256 + threadIdx.x;
    if (idx >= NN * 16) return;
    int i = idx >> 4;
    float di = dinv[i];
    float4 v = ((float4*)y)[idx];
    v.x *= di; v.y *= di; v.z *= di; v.w *= di;
    ((float4*)y)[idx] = v;
    ((float4*)Z)[idx] = v;
}

// out_mu[i][c] = dinv[i]*Z[i][c]    + b_mu[c]   (c in 0..31)
// out_ls[i][c] = dinv[i]*Z[i][c+32] + b_ls[c]
__global__ __launch_bounds__(256)
void final_k(const float* __restrict__ Z, const float* __restrict__ dinv,
             const float* __restrict__ b_mu, const float* __restrict__ b_ls,
             float* __restrict__ out)
{
    int idx = blockIdx.x * 256 + threadIdx.x;
    if (idx >= NN * 16) return;
    int i  = idx >> 4;
    int c4 = (idx & 15) << 2;
    float di = dinv[i];
    float4 z = ((const float4*)Z)[idx];
    float4 r;
    if (c4 < 32) {
        const float4 b = *(const float4*)&b_mu[c4];
        r.x = di * z.x + b.x; r.y = di * z.y + b.y;
        r.z = di * z.z + b.z; r.w = di * z.w + b.w;
        *(float4*)&out[(size_t)i * 32 + c4] = r;
    } else {
        const float4 b = *(const float4*)&b_ls[c4 - 32];
        r.x = di * z.x + b.x; r.y = di * z.y + b.y;
        r.z = di * z.z + b.z; r.w = di * z.w + b.w;
        *(float4*)&out[(size_t)NN * 32 + (size_t)i * 32 + (c4 - 32)] = r;
    }
}

extern "C" void kernel_launch(void* const* d_in, const int* in_sizes, int n_in,
                              void* d_out, int out_size, void* d_ws, size_t ws_size,
                              hipStream_t stream)
{
    (void)in_sizes; (void)n_in; (void)out_size; (void)ws_size;
    const float* x       = (const float*)d_in[0];
    const int*   ei      = (const int*)d_in[1];
    const int*   srcv    = ei;
    const int*   dstv    = ei + NE;
    const float* w1_rel  = (const float*)d_in[2];
    const float* w1_root = (const float*)d_in[3];
    const float* b1      = (const float*)d_in[4];
    const float* w2_rel  = (const float*)d_in[5];
    const float* w2_root = (const float*)d_in[6];
    const float* b2      = (const float*)d_in[7];
    const float* w_mu    = (const float*)d_in[8];
    const float* b_mu    = (const float*)d_in[9];
    const float* w_ls    = (const float*)d_in[10];
    const float* b_ls    = (const float*)d_in[11];
    float* out = (float*)d_out;

    char* ws = (char*)d_ws;
    float* W0   = (float*)(ws);               // N*96 : t1, later y/yscaled (N*64)
    float* W1   = (float*)(ws + 19200000);    // N*96 : h1
    float* W2   = (float*)(ws + 38400000);    // N*64 : t2, later Z
    float* W3   = (float*)(ws + 51200000);    // N*64 : h2
    float* dinv = (float*)(ws + 64000000);    // N
    int*   deg  = (int*)  (ws + 64200000);    // N

    // degrees + normalization (independent of layers; needed before scale_init)
    hipMemsetAsync(deg, 0, NN * sizeof(int), stream);
    count_deg_k<<<(NE + 255) / 256, 256, 0, stream>>>(dstv, deg);
    dinv_k<<<(NN + 255) / 256, 256, 0, stream>>>(deg, dinv);

    // layer 1: t1 = x@w1_rel -> W0 ; h1pre = x@w1_root + b1 -> W1
    gemm_dual<128><<<dim3(782, 6), 256, 0, stream>>>(x, w1_rel, w1_root, b1, W0, W1, 96, 96);
    scatter_add_k<96><<<(NE * 24 + 255) / 256, 256, 0, stream>>>(srcv, dstv, W0, W1);
    relu_k<<<(NN * 24 + 255) / 256, 256, 0, stream>>>((float4*)W1, NN * 24);

    // layer 2: t2 = h1@w2_rel -> W2 ; h2pre = h1@w2_root + b2 -> W3
    gemm_dual<96><<<dim3(782, 4), 256, 0, stream>>>(W1, w2_rel, w2_root, b2, W2, W3, 64, 64);
    scatter_add_k<64><<<(NE * 16 + 255) / 256, 256, 0, stream>>>(srcv, dstv, W2, W3);
    relu_k<<<(NN * 16 + 255) / 256, 256, 0, stream>>>((float4*)W3, NN * 16);

    // layer 3: y = h2 @ [w_mu | w_ls] -> W0 (stride 64), no bias here
    gemm_dual<64><<<dim3(782, 2), 256, 0, stream>>>(W3, w_mu, w_ls, nullptr, W0, W0 + 32, 32, 64);
    // yscaled = dinv*y (in place), Z init with self-loop term
    scale_init_k<<<(NN * 16 + 255) / 256, 256, 0, stream>>>(W0, dinv, W2);
    scatter_add_k<64><<<(NE * 16 + 255) / 256, 256, 0, stream>>>(srcv, dstv, W0, W2);
    final_k<<<(NN * 16 + 255) / 256, 256, 0, stream>>>(W2, dinv, b_mu, b_ls, out);
}

// Round 2
// 495.756 us; speedup vs baseline: 3.8859x; 3.8859x over previous
//
#include <hip/hip_runtime.h>
#include <cstddef>

static constexpr int NN = 50000;
static constexpr int NE = 600000;

// ---------------- degree / norm ----------------
__global__ __launch_bounds__(256)
void count_deg_k(const int* __restrict__ dstv, int* __restrict__ deg) {
    int e = blockIdx.x * 256 + threadIdx.x;
    if (e < NE) atomicAdd(&deg[dstv[e]], 1);
}

__global__ __launch_bounds__(256)
void dinv_k(const int* __restrict__ deg, float* __restrict__ dinv) {
    int i = blockIdx.x * 256 + threadIdx.x;
    if (i < NN) dinv[i] = rsqrtf((float)deg[i] + 1.0f);  // +1 self-loop
}

// ---------------- single-block exclusive scan: deg -> row_start, cursor ----
__global__ __launch_bounds__(256)
void scan_k(const int* __restrict__ deg, int* __restrict__ row_start,
            int* __restrict__ cursor)
{
    __shared__ int buf[256];
    __shared__ int carry_s;
    if (threadIdx.x == 0) carry_s = 0;
    __syncthreads();
    for (int base = 0; base < NN; base += 256) {
        int i = base + threadIdx.x;
        int v = (i < NN) ? deg[i] : 0;
        buf[threadIdx.x] = v;
        __syncthreads();
        // Hillis-Steele inclusive scan
        #pragma unroll
        for (int off = 1; off < 256; off <<= 1) {
            int t = (threadIdx.x >= off) ? buf[threadIdx.x - off] : 0;
            __syncthreads();
            buf[threadIdx.x] += t;
            __syncthreads();
        }
        int incl = buf[threadIdx.x];
        int excl = incl - v;
        int c = carry_s;
        if (i < NN) { row_start[i] = c + excl; cursor[i] = c + excl; }
        __syncthreads();
        if (threadIdx.x == 255) carry_s = c + buf[255];
        __syncthreads();
    }
    if (threadIdx.x == 0) row_start[NN] = carry_s;   // == NE
}

// ---------------- CSR fill (int atomics on cursor) ----------------
__global__ __launch_bounds__(256)
void fill_k(const int* __restrict__ srcv, const int* __restrict__ dstv,
            int* __restrict__ cursor, int* __restrict__ csr)
{
    int e = blockIdx.x * 256 + threadIdx.x;
    if (e < NE) {
        int pos = atomicAdd(&cursor[dstv[e]], 1);
        csr[pos] = srcv[e];
    }
}

// ---------------- fused dual GEMM ----------------
// outA = X @ Wa ; outB = X @ Wb (+ biasB). Optional per-node scale on store.
template<int K>
__global__ __launch_bounds__(256)
void gemm_dual(const float* __restrict__ X,
               const float* __restrict__ Wa,
               const float* __restrict__ Wb,
               const float* __restrict__ biasB,
               const float* __restrict__ scale,
               float* __restrict__ outA,
               float* __restrict__ outB,
               int OC, int ostride)
{
    __shared__ float Ws[K * 32];
    const int nchunk = OC >> 5;
    const int chunk  = blockIdx.y;
    const int mat    = chunk / nchunk;            // 0 = Wa, 1 = Wb
    const int c0     = (chunk % nchunk) << 5;
    const float* __restrict__ W = mat ? Wb : Wa;
    for (int i = threadIdx.x; i < K * 32; i += 256) {
        int k = i >> 5, cl = i & 31;
        Ws[i] = W[k * OC + c0 + cl];
    }
    __syncthreads();

    const int nl  = threadIdx.x >> 3;             // 0..31 node lane
    const int cl4 = (threadIdx.x & 7) << 2;       // channel*4 within chunk

    float bx = 0.f, by = 0.f, bz = 0.f, bw = 0.f;
    if (mat && biasB) {
        bx = biasB[c0 + cl4 + 0];
        by = biasB[c0 + cl4 + 1];
        bz = biasB[c0 + cl4 + 2];
        bw = biasB[c0 + cl4 + 3];
    }
    float* __restrict__ outp = mat ? outB : outA;

    for (int ni = 0; ni < 2; ++ni) {
        int node = blockIdx.x * 64 + ni * 32 + nl;
        if (node >= NN) break;
        const float4* __restrict__ xr = (const float4*)(X + (size_t)node * K);
        float ax = bx, ay = by, az = bz, aw = bw;
        #pragma unroll 4
        for (int k4 = 0; k4 < K / 4; ++k4) {
            float4 xv = xr[k4];
            float xk[4] = {xv.x, xv.y, xv.z, xv.w};
            #pragma unroll
            for (int j = 0; j < 4; ++j) {
                const float4 wv = *(const float4*)&Ws[((k4 << 2) + j) * 32 + cl4];
                ax = fmaf(xk[j], wv.x, ax);
                ay = fmaf(xk[j], wv.y, ay);
                az = fmaf(xk[j], wv.z, az);
                aw = fmaf(xk[j], wv.w, aw);
            }
        }
        if (scale) {
            float s = scale[node];
            ax *= s; ay *= s; az *= s; aw *= s;
        }
        float4 r = {ax, ay, az, aw};
        *(float4*)&outp[(size_t)node * ostride + c0 + cl4] = r;
    }
}

// ---------------- gather-side aggregation + relu ----------------
// hio in: h_pre (root term + bias); out: relu(h_pre + sum_{j->i} msg[j])
template<int OC>
__global__ __launch_bounds__(256)
void gather_relu_k(const int* __restrict__ row_start,
                   const int* __restrict__ csr,
                   const float* __restrict__ msg,
                   float* __restrict__ hio)
{
    constexpr int CP = OC / 4;
    int idx = blockIdx.x * 256 + threadIdx.x;
    if (idx >= NN * CP) return;
    int i  = idx / CP;
    int c4 = (idx % CP) << 2;
    int e0 = row_start[i], e1 = row_start[i + 1];
    float4 a = *(const float4*)&hio[(size_t)i * OC + c4];
    for (int e = e0; e < e1; ++e) {
        int s = csr[e];
        const float4 v = *(const float4*)&msg[(size_t)s * OC + c4];
        a.x += v.x; a.y += v.y; a.z += v.z; a.w += v.w;
    }
    a.x = fmaxf(a.x, 0.f); a.y = fmaxf(a.y, 0.f);
    a.z = fmaxf(a.z, 0.f); a.w = fmaxf(a.w, 0.f);
    *(float4*)&hio[(size_t)i * OC + c4] = a;
}

// ---------------- GCN gather: out = dinv_i*(y_i + sum y_j) + bias, split ----
__global__ __launch_bounds__(256)
void gather_gcn_k(const int* __restrict__ row_start,
                  const int* __restrict__ csr,
                  const float* __restrict__ y,      // pre-scaled by dinv
                  const float* __restrict__ dinv,
                  const float* __restrict__ b_mu,
                  const float* __restrict__ b_ls,
                  float* __restrict__ out)
{
    int idx = blockIdx.x * 256 + threadIdx.x;
    if (idx >= NN * 16) return;
    int i  = idx >> 4;
    int c4 = (idx & 15) << 2;
    int e0 = row_start[i], e1 = row_start[i + 1];
    float4 a = *(const float4*)&y[(size_t)i * 64 + c4];   // self-loop term
    for (int e = e0; e < e1; ++e) {
        int s = csr[e];
        const float4 v = *(const float4*)&y[(size_t)s * 64 + c4];
        a.x += v.x; a.y += v.y; a.z += v.z; a.w += v.w;
    }
    float di = dinv[i];
    if (c4 < 32) {
        const float4 b = *(const float4*)&b_mu[c4];
        float4 r = {di * a.x + b.x, di * a.y + b.y, di * a.z + b.z, di * a.w + b.w};
        *(float4*)&out[(size_t)i * 32 + c4] = r;
    } else {
        const float4 b = *(const float4*)&b_ls[c4 - 32];
        float4 r = {di * a.x + b.x, di * a.y + b.y, di * a.z + b.z, di * a.w + b.w};
        *(float4*)&out[(size_t)NN * 32 + (size_t)i * 32 + (c4 - 32)] = r;
    }
}

extern "C" void kernel_launch(void* const* d_in, const int* in_sizes, int n_in,
                              void* d_out, int out_size, void* d_ws, size_t ws_size,
                              hipStream_t stream)
{
    (void)in_sizes; (void)n_in; (void)out_size; (void)ws_size;
    const float* x       = (const float*)d_in[0];
    const int*   ei      = (const int*)d_in[1];
    const int*   srcv    = ei;
    const int*   dstv    = ei + NE;
    const float* w1_rel  = (const float*)d_in[2];
    const float* w1_root = (const float*)d_in[3];
    const float* b1      = (const float*)d_in[4];
    const float* w2_rel  = (const float*)d_in[5];
    const float* w2_root = (const float*)d_in[6];
    const float* b2      = (const float*)d_in[7];
    const float* w_mu    = (const float*)d_in[8];
    const float* b_mu    = (const float*)d_in[9];
    const float* w_ls    = (const float*)d_in[10];
    const float* b_ls    = (const float*)d_in[11];
    float* out = (float*)d_out;

    char* ws = (char*)d_ws;
    float* A    = (float*)(ws);               // 19.2MB: t1 -> t2 -> y
    float* B    = (float*)(ws + 19200000);    // 19.2MB: h1pre -> h1
    float* C    = (float*)(ws + 38400000);    // 12.8MB: h2pre -> h2
    int* csr       = (int*)(ws + 51200000);   // 2.4MB
    int* row_start = (int*)(ws + 53600000);   // (NN+1)*4
    int* cursor    = (int*)(ws + 53800016);   // NN*4
    float* dinv    = (float*)(ws + 54000016); // NN*4
    int* deg       = (int*)(ws + 54200016);   // NN*4

    // ---- CSR build + norm ----
    hipMemsetAsync(deg, 0, NN * sizeof(int), stream);
    count_deg_k<<<(NE + 255) / 256, 256, 0, stream>>>(dstv, deg);
    dinv_k<<<(NN + 255) / 256, 256, 0, stream>>>(deg, dinv);
    scan_k<<<1, 256, 0, stream>>>(deg, row_start, cursor);
    fill_k<<<(NE + 255) / 256, 256, 0, stream>>>(srcv, dstv, cursor, csr);

    // ---- layer 1: t1 = x@w1_rel -> A ; h1pre = x@w1_root + b1 -> B ----
    gemm_dual<128><<<dim3(782, 6), 256, 0, stream>>>(x, w1_rel, w1_root, b1, nullptr, A, B, 96, 96);
    gather_relu_k<96><<<(NN * 24 + 255) / 256, 256, 0, stream>>>(row_start, csr, A, B);

    // ---- layer 2: t2 = h1@w2_rel -> A ; h2pre = h1@w2_root + b2 -> C ----
    gemm_dual<96><<<dim3(782, 4), 256, 0, stream>>>(B, w2_rel, w2_root, b2, nullptr, A, C, 64, 64);
    gather_relu_k<64><<<(NN * 16 + 255) / 256, 256, 0, stream>>>(row_start, csr, A, C);

    // ---- layer 3: y = dinv * (h2 @ [w_mu | w_ls]) -> A (stride 64) ----
    gemm_dual<64><<<dim3(782, 2), 256, 0, stream>>>(C, w_mu, w_ls, nullptr, dinv, A, A + 32, 32, 64);
    gather_gcn_k<<<(NN * 16 + 255) / 256, 256, 0, stream>>>(row_start, csr, A, dinv, b_mu, b_ls, out);
}

// Round 3
// 291.482 us; speedup vs baseline: 6.6092x; 1.7008x over previous
//
#include <hip/hip_runtime.h>
#include <cstddef>

static constexpr int NN = 50000;
static constexpr int NE = 600000;
static constexpr int NB = (NN + 255) / 256;   // 196 scan blocks

// ---------------- degree count ----------------
__global__ __launch_bounds__(256)
void count_deg_k(const int* __restrict__ dstv, int* __restrict__ deg) {
    int e = blockIdx.x * 256 + threadIdx.x;
    if (e < NE) atomicAdd(&deg[dstv[e]], 1);
}

// ---------------- hierarchical scan ----------------
// A: per-block reduce deg -> partial[b]
__global__ __launch_bounds__(256)
void scan_reduce_k(const int* __restrict__ deg, int* __restrict__ partial) {
    __shared__ int buf[256];
    int i = blockIdx.x * 256 + threadIdx.x;
    buf[threadIdx.x] = (i < NN) ? deg[i] : 0;
    __syncthreads();
    #pragma unroll
    for (int off = 128; off > 0; off >>= 1) {
        if (threadIdx.x < off) buf[threadIdx.x] += buf[threadIdx.x + off];
        __syncthreads();
    }
    if (threadIdx.x == 0) partial[blockIdx.x] = buf[0];
}

// B: single-block exclusive scan of NB partials; row_start[NN] = total
__global__ __launch_bounds__(256)
void scan_partials_k(int* __restrict__ partial, int* __restrict__ row_start) {
    __shared__ int buf[256];
    int t = threadIdx.x;
    int v = (t < NB) ? partial[t] : 0;
    buf[t] = v;
    __syncthreads();
    #pragma unroll
    for (int off = 1; off < 256; off <<= 1) {
        int tv = (t >= off) ? buf[t - off] : 0;
        __syncthreads();
        buf[t] += tv;
        __syncthreads();
    }
    if (t < NB) partial[t] = buf[t] - v;          // exclusive
    if (t == 255) row_start[NN] = buf[255];       // total == NE
}

// C: per-block scan + offset -> row_start/cursor ; fused dinv = rsqrt(deg+1)
__global__ __launch_bounds__(256)
void scan_final_k(const int* __restrict__ deg, const int* __restrict__ partial,
                  int* __restrict__ row_start, int* __restrict__ cursor,
                  float* __restrict__ dinv) {
    __shared__ int buf[256];
    int i = blockIdx.x * 256 + threadIdx.x;
    int t = threadIdx.x;
    int v = (i < NN) ? deg[i] : 0;
    buf[t] = v;
    __syncthreads();
    #pragma unroll
    for (int off = 1; off < 256; off <<= 1) {
        int tv = (t >= off) ? buf[t - off] : 0;
        __syncthreads();
        buf[t] += tv;
        __syncthreads();
    }
    if (i < NN) {
        int pos = partial[blockIdx.x] + buf[t] - v;   // block offset + excl
        row_start[i] = pos;
        cursor[i] = pos;
        dinv[i] = rsqrtf((float)v + 1.0f);            // +1 self-loop
    }
}

// ---------------- CSR fill (int atomics on cursor) ----------------
__global__ __launch_bounds__(256)
void fill_k(const int* __restrict__ srcv, const int* __restrict__ dstv,
            int* __restrict__ cursor, int* __restrict__ csr)
{
    int e = blockIdx.x * 256 + threadIdx.x;
    if (e < NE) {
        int pos = atomicAdd(&cursor[dstv[e]], 1);
        csr[pos] = srcv[e];
    }
}

// ---------------- fused dual GEMM ----------------
// outA = X @ Wa ; outB = X @ Wb (+ biasB). Optional per-node scale on store.
template<int K>
__global__ __launch_bounds__(256)
void gemm_dual(const float* __restrict__ X,
               const float* __restrict__ Wa,
               const float* __restrict__ Wb,
               const float* __restrict__ biasB,
               const float* __restrict__ scale,
               float* __restrict__ outA,
               float* __restrict__ outB,
               int OC, int ostride)
{
    __shared__ float Ws[K * 32];
    const int nchunk = OC >> 5;
    const int chunk  = blockIdx.y;
    const int mat    = chunk / nchunk;            // 0 = Wa, 1 = Wb
    const int c0     = (chunk % nchunk) << 5;
    const float* __restrict__ W = mat ? Wb : Wa;
    for (int i = threadIdx.x; i < K * 32; i += 256) {
        int k = i >> 5, cl = i & 31;
        Ws[i] = W[k * OC + c0 + cl];
    }
    __syncthreads();

    const int nl  = threadIdx.x >> 3;             // 0..31 node lane
    const int cl4 = (threadIdx.x & 7) << 2;       // channel*4 within chunk

    float bx = 0.f, by = 0.f, bz = 0.f, bw = 0.f;
    if (mat && biasB) {
        bx = biasB[c0 + cl4 + 0];
        by = biasB[c0 + cl4 + 1];
        bz = biasB[c0 + cl4 + 2];
        bw = biasB[c0 + cl4 + 3];
    }
    float* __restrict__ outp = mat ? outB : outA;

    for (int ni = 0; ni < 2; ++ni) {
        int node = blockIdx.x * 64 + ni * 32 + nl;
        if (node >= NN) break;
        const float4* __restrict__ xr = (const float4*)(X + (size_t)node * K);
        float ax = bx, ay = by, az = bz, aw = bw;
        #pragma unroll 4
        for (int k4 = 0; k4 < K / 4; ++k4) {
            float4 xv = xr[k4];
            float xk[4] = {xv.x, xv.y, xv.z, xv.w};
            #pragma unroll
            for (int j = 0; j < 4; ++j) {
                const float4 wv = *(const float4*)&Ws[((k4 << 2) + j) * 32 + cl4];
                ax = fmaf(xk[j], wv.x, ax);
                ay = fmaf(xk[j], wv.y, ay);
                az = fmaf(xk[j], wv.z, az);
                aw = fmaf(xk[j], wv.w, aw);
            }
        }
        if (scale) {
            float s = scale[node];
            ax *= s; ay *= s; az *= s; aw *= s;
        }
        float4 r = {ax, ay, az, aw};
        *(float4*)&outp[(size_t)node * ostride + c0 + cl4] = r;
    }
}

// ---------------- gather-side aggregation + relu ----------------
template<int OC>
__global__ __launch_bounds__(256)
void gather_relu_k(const int* __restrict__ row_start,
                   const int* __restrict__ csr,
                   const float* __restrict__ msg,
                   float* __restrict__ hio)
{
    constexpr int CP = OC / 4;
    int idx = blockIdx.x * 256 + threadIdx.x;
    if (idx >= NN * CP) return;
    int i  = idx / CP;
    int c4 = (idx % CP) << 2;
    int e0 = row_start[i], e1 = row_start[i + 1];
    float4 a = *(const float4*)&hio[(size_t)i * OC + c4];
    for (int e = e0; e < e1; ++e) {
        int s = csr[e];
        const float4 v = *(const float4*)&msg[(size_t)s * OC + c4];
        a.x += v.x; a.y += v.y; a.z += v.z; a.w += v.w;
    }
    a.x = fmaxf(a.x, 0.f); a.y = fmaxf(a.y, 0.f);
    a.z = fmaxf(a.z, 0.f); a.w = fmaxf(a.w, 0.f);
    *(float4*)&hio[(size_t)i * OC + c4] = a;
}

// ---------------- GCN gather: out = dinv_i*(y_i + sum y_j) + bias, split ----
__global__ __launch_bounds__(256)
void gather_gcn_k(const int* __restrict__ row_start,
                  const int* __restrict__ csr,
                  const float* __restrict__ y,      // pre-scaled by dinv
                  const float* __restrict__ dinv,
                  const float* __restrict__ b_mu,
                  const float* __restrict__ b_ls,
                  float* __restrict__ out)
{
    int idx = blockIdx.x * 256 + threadIdx.x;
    if (idx >= NN * 16) return;
    int i  = idx >> 4;
    int c4 = (idx & 15) << 2;
    int e0 = row_start[i], e1 = row_start[i + 1];
    float4 a = *(const float4*)&y[(size_t)i * 64 + c4];   // self-loop term
    for (int e = e0; e < e1; ++e) {
        int s = csr[e];
        const float4 v = *(const float4*)&y[(size_t)s * 64 + c4];
        a.x += v.x; a.y += v.y; a.z += v.z; a.w += v.w;
    }
    float di = dinv[i];
    if (c4 < 32) {
        const float4 b = *(const float4*)&b_mu[c4];
        float4 r = {di * a.x + b.x, di * a.y + b.y, di * a.z + b.z, di * a.w + b.w};
        *(float4*)&out[(size_t)i * 32 + c4] = r;
    } else {
        const float4 b = *(const float4*)&b_ls[c4 - 32];
        float4 r = {di * a.x + b.x, di * a.y + b.y, di * a.z + b.z, di * a.w + b.w};
        *(float4*)&out[(size_t)NN * 32 + (size_t)i * 32 + (c4 - 32)] = r;
    }
}

extern "C" void kernel_launch(void* const* d_in, const int* in_sizes, int n_in,
                              void* d_out, int out_size, void* d_ws, size_t ws_size,
                              hipStream_t stream)
{
    (void)in_sizes; (void)n_in; (void)out_size; (void)ws_size;
    const float* x       = (const float*)d_in[0];
    const int*   ei      = (const int*)d_in[1];
    const int*   srcv    = ei;
    const int*   dstv    = ei + NE;
    const float* w1_rel  = (const float*)d_in[2];
    const float* w1_root = (const float*)d_in[3];
    const float* b1      = (const float*)d_in[4];
    const float* w2_rel  = (const float*)d_in[5];
    const float* w2_root = (const float*)d_in[6];
    const float* b2      = (const float*)d_in[7];
    const float* w_mu    = (const float*)d_in[8];
    const float* b_mu    = (const float*)d_in[9];
    const float* w_ls    = (const float*)d_in[10];
    const float* b_ls    = (const float*)d_in[11];
    float* out = (float*)d_out;

    char* ws = (char*)d_ws;
    float* A    = (float*)(ws);               // 19.2MB: t1 -> t2 -> y
    float* B    = (float*)(ws + 19200000);    // 19.2MB: h1pre -> h1
    float* C    = (float*)(ws + 38400000);    // 12.8MB: h2pre -> h2
    int* csr       = (int*)(ws + 51200000);   // 2.4MB
    int* row_start = (int*)(ws + 53600000);   // (NN+1)*4
    int* cursor    = (int*)(ws + 53800016);   // NN*4
    float* dinv    = (float*)(ws + 54000016); // NN*4
    int* deg       = (int*)(ws + 54200016);   // NN*4
    int* partial   = (int*)(ws + 54400016);   // NB*4

    // ---- CSR build + norm ----
    hipMemsetAsync(deg, 0, NN * sizeof(int), stream);
    count_deg_k<<<(NE + 255) / 256, 256, 0, stream>>>(dstv, deg);
    scan_reduce_k<<<NB, 256, 0, stream>>>(deg, partial);
    scan_partials_k<<<1, 256, 0, stream>>>(partial, row_start);
    scan_final_k<<<NB, 256, 0, stream>>>(deg, partial, row_start, cursor, dinv);
    fill_k<<<(NE + 255) / 256, 256, 0, stream>>>(srcv, dstv, cursor, csr);

    // ---- layer 1: t1 = x@w1_rel -> A ; h1pre = x@w1_root + b1 -> B ----
    gemm_dual<128><<<dim3(782, 6), 256, 0, stream>>>(x, w1_rel, w1_root, b1, nullptr, A, B, 96, 96);
    gather_relu_k<96><<<(NN * 24 + 255) / 256, 256, 0, stream>>>(row_start, csr, A, B);

    // ---- layer 2: t2 = h1@w2_rel -> A ; h2pre = h1@w2_root + b2 -> C ----
    gemm_dual<96><<<dim3(782, 4), 256, 0, stream>>>(B, w2_rel, w2_root, b2, nullptr, A, C, 64, 64);
    gather_relu_k<64><<<(NN * 16 + 255) / 256, 256, 0, stream>>>(row_start, csr, A, C);

    // ---- layer 3: y = dinv * (h2 @ [w_mu | w_ls]) -> A (stride 64) ----
    gemm_dual<64><<<dim3(782, 2), 256, 0, stream>>>(C, w_mu, w_ls, nullptr, dinv, A, A + 32, 32, 64);
    gather_gcn_k<<<(NN * 16 + 255) / 256, 256, 0, stream>>>(row_start, csr, A, dinv, b_mu, b_ls, out);
}

// Round 4
// 271.020 us; speedup vs baseline: 7.1082x; 1.0755x over previous
//
#include <hip/hip_runtime.h>
#include <cstddef>

static constexpr int NN = 50000;
static constexpr int NE = 600000;
static constexpr int NB = (NN + 255) / 256;   // 196 scan blocks

// ---------------- bf16 helpers (manual, RNE) ----------------
__device__ inline float bf2f(unsigned short u) {
    return __uint_as_float(((unsigned)u) << 16);
}
__device__ inline unsigned short f2bf(float f) {
    unsigned u = __float_as_uint(f);
    unsigned r = u + 0x7fffu + ((u >> 16) & 1u);
    return (unsigned short)(r >> 16);
}
__device__ inline float lof(unsigned u) { return __uint_as_float(u << 16); }
__device__ inline float hif(unsigned u) { return __uint_as_float(u & 0xffff0000u); }
__device__ inline unsigned packbf(float a, float b) {
    return (unsigned)f2bf(a) | ((unsigned)f2bf(b) << 16);
}

// ---------------- degree count ----------------
__global__ __launch_bounds__(256)
void count_deg_k(const int* __restrict__ dstv, int* __restrict__ deg) {
    int e = blockIdx.x * 256 + threadIdx.x;
    if (e < NE) atomicAdd(&deg[dstv[e]], 1);
}

// ---------------- hierarchical scan ----------------
__global__ __launch_bounds__(256)
void scan_reduce_k(const int* __restrict__ deg, int* __restrict__ partial) {
    __shared__ int buf[256];
    int i = blockIdx.x * 256 + threadIdx.x;
    buf[threadIdx.x] = (i < NN) ? deg[i] : 0;
    __syncthreads();
    #pragma unroll
    for (int off = 128; off > 0; off >>= 1) {
        if (threadIdx.x < off) buf[threadIdx.x] += buf[threadIdx.x + off];
        __syncthreads();
    }
    if (threadIdx.x == 0) partial[blockIdx.x] = buf[0];
}

__global__ __launch_bounds__(256)
void scan_partials_k(int* __restrict__ partial, int* __restrict__ row_start) {
    __shared__ int buf[256];
    int t = threadIdx.x;
    int v = (t < NB) ? partial[t] : 0;
    buf[t] = v;
    __syncthreads();
    #pragma unroll
    for (int off = 1; off < 256; off <<= 1) {
        int tv = (t >= off) ? buf[t - off] : 0;
        __syncthreads();
        buf[t] += tv;
        __syncthreads();
    }
    if (t < NB) partial[t] = buf[t] - v;          // exclusive
    if (t == 255) row_start[NN] = buf[255];       // total == NE
}

__global__ __launch_bounds__(256)
void scan_final_k(const int* __restrict__ deg, const int* __restrict__ partial,
                  int* __restrict__ row_start, int* __restrict__ cursor,
                  float* __restrict__ dinv) {
    __shared__ int buf[256];
    int i = blockIdx.x * 256 + threadIdx.x;
    int t = threadIdx.x;
    int v = (i < NN) ? deg[i] : 0;
    buf[t] = v;
    __syncthreads();
    #pragma unroll
    for (int off = 1; off < 256; off <<= 1) {
        int tv = (t >= off) ? buf[t - off] : 0;
        __syncthreads();
        buf[t] += tv;
        __syncthreads();
    }
    if (i < NN) {
        int pos = partial[blockIdx.x] + buf[t] - v;
        row_start[i] = pos;
        cursor[i] = pos;
        dinv[i] = rsqrtf((float)v + 1.0f);        // +1 self-loop
    }
}

// ---------------- CSR fill ----------------
__global__ __launch_bounds__(256)
void fill_k(const int* __restrict__ srcv, const int* __restrict__ dstv,
            int* __restrict__ cursor, int* __restrict__ csr)
{
    int e = blockIdx.x * 256 + threadIdx.x;
    if (e < NE) {
        int pos = atomicAdd(&cursor[dstv[e]], 1);
        csr[pos] = srcv[e];
    }
}

// ---------------- tiled dual GEMM, bf16 out ----------------
// 128 nodes x OCC channels per block. Thread = 4 nodes x (OCC/8) channels.
// Non-SPLIT: blockIdx.y picks matrix (0: Wa->outA no bias, 1: Wb->outB +bias).
// SPLIT (layer3): Ws = [Wa(32) | Wb(32)], out outA, optional per-node scale.
template<int K, int OCC, bool XB, bool SPLIT>
__global__ __launch_bounds__(256)
void gemm_tile(const void* __restrict__ Xv,
               const float* __restrict__ Wa,
               const float* __restrict__ Wb,
               const float* __restrict__ biasB,
               const float* __restrict__ scale,
               unsigned short* __restrict__ outA,
               unsigned short* __restrict__ outB,
               int OSTR)
{
    __shared__ float Ws[K * OCC];
    const int tid = threadIdx.x;
    const int mat = SPLIT ? 0 : blockIdx.y;
    const float* bias = nullptr;
    if (SPLIT) {
        for (int i = tid; i < K * OCC; i += 256) {
            int k = i / OCC, c = i - k * OCC;
            Ws[i] = (c < 32) ? Wa[k * 32 + c] : Wb[k * 32 + (c - 32)];
        }
    } else {
        const float* W = mat ? Wb : Wa;
        for (int i = tid; i < K * OCC; i += 256) Ws[i] = W[i];
        if (mat) bias = biasB;
    }
    __syncthreads();

    constexpr int CPG = OCC / 8;      // channels per thread (12 or 8)
    constexpr int F4  = CPG / 4;      // float4 accumulators (3 or 2)
    const int slot = tid & 31, grp = tid >> 5;
    unsigned short* __restrict__ outp = (SPLIT || mat == 0) ? outA : outB;

    float4 acc[4][F4];
    {
        float4 binit[F4];
        #pragma unroll
        for (int f = 0; f < F4; ++f) {
            if (bias) binit[f] = *(const float4*)&bias[grp * CPG + 4 * f];
            else { binit[f].x = 0.f; binit[f].y = 0.f; binit[f].z = 0.f; binit[f].w = 0.f; }
        }
        #pragma unroll
        for (int i = 0; i < 4; ++i)
            #pragma unroll
            for (int f = 0; f < F4; ++f) acc[i][f] = binit[f];
    }

    int n[4]; bool vld[4];
    #pragma unroll
    for (int i = 0; i < 4; ++i) {
        int ni = blockIdx.x * 128 + slot + 32 * i;
        vld[i] = ni < NN;
        n[i] = vld[i] ? ni : (NN - 1);
    }
    const float* Xf = (const float*)Xv;
    const unsigned short* Xh = (const unsigned short*)Xv;

    for (int k4 = 0; k4 < K / 4; ++k4) {
        float xv[4][4];
        #pragma unroll
        for (int i = 0; i < 4; ++i) {
            if (XB) {
                ushort4 u = *(const ushort4*)&Xh[(size_t)n[i] * K + 4 * k4];
                xv[i][0] = bf2f(u.x); xv[i][1] = bf2f(u.y);
                xv[i][2] = bf2f(u.z); xv[i][3] = bf2f(u.w);
            } else {
                float4 v = *(const float4*)&Xf[(size_t)n[i] * K + 4 * k4];
                xv[i][0] = v.x; xv[i][1] = v.y; xv[i][2] = v.z; xv[i][3] = v.w;
            }
        }
        #pragma unroll
        for (int j = 0; j < 4; ++j) {
            const float* wr = &Ws[(4 * k4 + j) * OCC + grp * CPG];
            #pragma unroll
            for (int f = 0; f < F4; ++f) {
                const float4 wv = *(const float4*)&wr[4 * f];
                #pragma unroll
                for (int i = 0; i < 4; ++i) {
                    acc[i][f].x = fmaf(xv[i][j], wv.x, acc[i][f].x);
                    acc[i][f].y = fmaf(xv[i][j], wv.y, acc[i][f].y);
                    acc[i][f].z = fmaf(xv[i][j], wv.z, acc[i][f].z);
                    acc[i][f].w = fmaf(xv[i][j], wv.w, acc[i][f].w);
                }
            }
        }
    }

    #pragma unroll
    for (int i = 0; i < 4; ++i) {
        if (!vld[i]) continue;
        float s = scale ? scale[n[i]] : 1.0f;
        unsigned short* op = outp + (size_t)n[i] * OSTR + grp * CPG;
        #pragma unroll
        for (int f = 0; f < F4; ++f) {
            float4 a = acc[i][f];
            uint2 p;
            p.x = packbf(a.x * s, a.y * s);
            p.y = packbf(a.z * s, a.w * s);
            *(uint2*)&op[4 * f] = p;
        }
    }
}

// ---------------- gather + relu (bf16 msg/hio, f32 accumulate) ----------------
template<int OC>
__global__ __launch_bounds__(256)
void gather_relu_k(const int* __restrict__ row_start,
                   const int* __restrict__ csr,
                   const unsigned short* __restrict__ msg,
                   unsigned short* __restrict__ hio)
{
    constexpr int G = OC / 8;
    int idx = blockIdx.x * 256 + threadIdx.x;
    if (idx >= NN * G) return;
    int i  = idx / G;
    int c8 = (idx - i * G) * 8;
    const size_t ro = (size_t)i * OC + c8;
    float a[8];
    {
        uint4 h = *(const uint4*)&hio[ro];
        a[0] = lof(h.x); a[1] = hif(h.x); a[2] = lof(h.y); a[3] = hif(h.y);
        a[4] = lof(h.z); a[5] = hif(h.z); a[6] = lof(h.w); a[7] = hif(h.w);
    }
    int e0 = row_start[i], e1 = row_start[i + 1];
    for (int e = e0; e < e1; ++e) {
        int s = csr[e];
        uint4 v = *(const uint4*)&msg[(size_t)s * OC + c8];
        a[0] += lof(v.x); a[1] += hif(v.x); a[2] += lof(v.y); a[3] += hif(v.y);
        a[4] += lof(v.z); a[5] += hif(v.z); a[6] += lof(v.w); a[7] += hif(v.w);
    }
    uint4 o;
    o.x = packbf(fmaxf(a[0], 0.f), fmaxf(a[1], 0.f));
    o.y = packbf(fmaxf(a[2], 0.f), fmaxf(a[3], 0.f));
    o.z = packbf(fmaxf(a[4], 0.f), fmaxf(a[5], 0.f));
    o.w = packbf(fmaxf(a[6], 0.f), fmaxf(a[7], 0.f));
    *(uint4*)&hio[ro] = o;
}

// ---------------- GCN gather: out = dinv_i*(y_i + sum y_j) + bias ----------------
__global__ __launch_bounds__(256)
void gather_gcn_k(const int* __restrict__ row_start,
                  const int* __restrict__ csr,
                  const unsigned short* __restrict__ y,   // bf16, pre-scaled by dinv
                  const float* __restrict__ dinv,
                  const float* __restrict__ b_mu,
                  const float* __restrict__ b_ls,
                  float* __restrict__ out)
{
    int idx = blockIdx.x * 256 + threadIdx.x;
    if (idx >= NN * 8) return;
    int i  = idx >> 3;
    int c8 = (idx & 7) * 8;
    float a[8];
    {
        uint4 h = *(const uint4*)&y[(size_t)i * 64 + c8];
        a[0] = lof(h.x); a[1] = hif(h.x); a[2] = lof(h.y); a[3] = hif(h.y);
        a[4] = lof(h.z); a[5] = hif(h.z); a[6] = lof(h.w); a[7] = hif(h.w);
    }
    int e0 = row_start[i], e1 = row_start[i + 1];
    for (int e = e0; e < e1; ++e) {
        int s = csr[e];
        uint4 v = *(const uint4*)&y[(size_t)s * 64 + c8];
        a[0] += lof(v.x); a[1] += hif(v.x); a[2] += lof(v.y); a[3] += hif(v.y);
        a[4] += lof(v.z); a[5] += hif(v.z); a[6] += lof(v.w); a[7] += hif(v.w);
    }
    float di = dinv[i];
    const float* b;
    float* o;
    if (c8 < 32) { b = &b_mu[c8];      o = &out[(size_t)i * 32 + c8]; }
    else         { b = &b_ls[c8 - 32]; o = &out[(size_t)NN * 32 + (size_t)i * 32 + (c8 - 32)]; }
    float4 r0, r1;
    r0.x = di * a[0] + b[0]; r0.y = di * a[1] + b[1];
    r0.z = di * a[2] + b[2]; r0.w = di * a[3] + b[3];
    r1.x = di * a[4] + b[4]; r1.y = di * a[5] + b[5];
    r1.z = di * a[6] + b[6]; r1.w = di * a[7] + b[7];
    *(float4*)&o[0] = r0;
    *(float4*)&o[4] = r1;
}

extern "C" void kernel_launch(void* const* d_in, const int* in_sizes, int n_in,
                              void* d_out, int out_size, void* d_ws, size_t ws_size,
                              hipStream_t stream)
{
    (void)in_sizes; (void)n_in; (void)out_size; (void)ws_size;
    const float* x       = (const float*)d_in[0];
    const int*   ei      = (const int*)d_in[1];
    const int*   srcv    = ei;
    const int*   dstv    = ei + NE;
    const float* w1_rel  = (const float*)d_in[2];
    const float* w1_root = (const float*)d_in[3];
    const float* b1      = (const float*)d_in[4];
    const float* w2_rel  = (const float*)d_in[5];
    const float* w2_root = (const float*)d_in[6];
    const float* b2      = (const float*)d_in[7];
    const float* w_mu    = (const float*)d_in[8];
    const float* b_mu    = (const float*)d_in[9];
    const float* w_ls    = (const float*)d_in[10];
    const float* b_ls    = (const float*)d_in[11];
    float* out = (float*)d_out;

    char* ws = (char*)d_ws;
    unsigned short* t1 = (unsigned short*)(ws);              // 9.6MB  NN*96 bf16
    unsigned short* h1 = (unsigned short*)(ws + 9600000);    // 9.6MB
    unsigned short* t2 = (unsigned short*)(ws + 19200000);   // 6.4MB  NN*64 bf16
    unsigned short* h2 = (unsigned short*)(ws + 25600000);   // 6.4MB
    unsigned short* y  = (unsigned short*)(ws + 32000000);   // 6.4MB
    int* csr       = (int*)(ws + 38400000);                  // 2.4MB
    int* row_start = (int*)(ws + 40800000);                  // (NN+1)*4
    int* cursor    = (int*)(ws + 41000016);                  // NN*4
    float* dinv    = (float*)(ws + 41200016);                // NN*4
    int* deg       = (int*)(ws + 41400016);                  // NN*4
    int* partial   = (int*)(ws + 41600016);                  // NB*4

    // ---- CSR build + norm ----
    hipMemsetAsync(deg, 0, NN * sizeof(int), stream);
    count_deg_k<<<(NE + 255) / 256, 256, 0, stream>>>(dstv, deg);
    scan_reduce_k<<<NB, 256, 0, stream>>>(deg, partial);
    scan_partials_k<<<1, 256, 0, stream>>>(partial, row_start);
    scan_final_k<<<NB, 256, 0, stream>>>(deg, partial, row_start, cursor, dinv);
    fill_k<<<(NE + 255) / 256, 256, 0, stream>>>(srcv, dstv, cursor, csr);

    const int NGB = (NN + 127) / 128;   // 391 node tiles

    // ---- layer 1: t1 = x@w1_rel ; h1 = x@w1_root + b1 (bf16 out) ----
    gemm_tile<128, 96, false, false><<<dim3(NGB, 2), 256, 0, stream>>>(
        x, w1_rel, w1_root, b1, nullptr, t1, h1, 96);
    gather_relu_k<96><<<(NN * 12 + 255) / 256, 256, 0, stream>>>(row_start, csr, t1, h1);

    // ---- layer 2: t2 = h1@w2_rel ; h2 = h1@w2_root + b2 ----
    gemm_tile<96, 64, true, false><<<dim3(NGB, 2), 256, 0, stream>>>(
        h1, w2_rel, w2_root, b2, nullptr, t2, h2, 64);
    gather_relu_k<64><<<(NN * 8 + 255) / 256, 256, 0, stream>>>(row_start, csr, t2, h2);

    // ---- layer 3: y = dinv * (h2 @ [w_mu | w_ls]) ----
    gemm_tile<64, 64, true, true><<<dim3(NGB, 1), 256, 0, stream>>>(
        h2, w_mu, w_ls, nullptr, dinv, y, nullptr, 64);
    gather_gcn_k<<<(NN * 8 + 255) / 256, 256, 0, stream>>>(row_start, csr, y, dinv, b_mu, b_ls, out);
}

// Round 5
// 191.321 us; speedup vs baseline: 10.0693x; 1.4166x over previous
//
#include <hip/hip_runtime.h>
#include <cstddef>

static constexpr int NN = 50000;
static constexpr int NE = 600000;
static constexpr int NB = (NN + 255) / 256;   // 196 scan blocks

using f32x4 = __attribute__((ext_vector_type(4))) float;
using s16x8 = __attribute__((ext_vector_type(8))) short;

// ---------------- bf16 helpers (manual, RNE) ----------------
__device__ inline float bf2f(unsigned short u) {
    return __uint_as_float(((unsigned)u) << 16);
}
__device__ inline unsigned short f2bf(float f) {
    unsigned u = __float_as_uint(f);
    unsigned r = u + 0x7fffu + ((u >> 16) & 1u);
    return (unsigned short)(r >> 16);
}
__device__ inline float lof(unsigned u) { return __uint_as_float(u << 16); }
__device__ inline float hif(unsigned u) { return __uint_as_float(u & 0xffff0000u); }
__device__ inline unsigned packbf(float a, float b) {
    return (unsigned)f2bf(a) | ((unsigned)f2bf(b) << 16);
}

// ---------------- degree count ----------------
__global__ __launch_bounds__(256)
void count_deg_k(const int* __restrict__ dstv, int* __restrict__ deg) {
    int e = blockIdx.x * 256 + threadIdx.x;
    if (e < NE) atomicAdd(&deg[dstv[e]], 1);
}

// ---------------- hierarchical scan ----------------
__global__ __launch_bounds__(256)
void scan_reduce_k(const int* __restrict__ deg, int* __restrict__ partial) {
    __shared__ int buf[256];
    int i = blockIdx.x * 256 + threadIdx.x;
    buf[threadIdx.x] = (i < NN) ? deg[i] : 0;
    __syncthreads();
    #pragma unroll
    for (int off = 128; off > 0; off >>= 1) {
        if (threadIdx.x < off) buf[threadIdx.x] += buf[threadIdx.x + off];
        __syncthreads();
    }
    if (threadIdx.x == 0) partial[blockIdx.x] = buf[0];
}

__global__ __launch_bounds__(256)
void scan_partials_k(int* __restrict__ partial, int* __restrict__ row_start) {
    __shared__ int buf[256];
    int t = threadIdx.x;
    int v = (t < NB) ? partial[t] : 0;
    buf[t] = v;
    __syncthreads();
    #pragma unroll
    for (int off = 1; off < 256; off <<= 1) {
        int tv = (t >= off) ? buf[t - off] : 0;
        __syncthreads();
        buf[t] += tv;
        __syncthreads();
    }
    if (t < NB) partial[t] = buf[t] - v;          // exclusive
    if (t == 255) row_start[NN] = buf[255];       // total == NE
}

__global__ __launch_bounds__(256)
void scan_final_k(const int* __restrict__ deg, const int* __restrict__ partial,
                  int* __restrict__ row_start, int* __restrict__ cursor,
                  float* __restrict__ dinv) {
    __shared__ int buf[256];
    int i = blockIdx.x * 256 + threadIdx.x;
    int t = threadIdx.x;
    int v = (i < NN) ? deg[i] : 0;
    buf[t] = v;
    __syncthreads();
    #pragma unroll
    for (int off = 1; off < 256; off <<= 1) {
        int tv = (t >= off) ? buf[t - off] : 0;
        __syncthreads();
        buf[t] += tv;
        __syncthreads();
    }
    if (i < NN) {
        int pos = partial[blockIdx.x] + buf[t] - v;
        row_start[i] = pos;
        cursor[i] = pos;
        dinv[i] = rsqrtf((float)v + 1.0f);        // +1 self-loop
    }
}

// ---------------- CSR fill ----------------
__global__ __launch_bounds__(256)
void fill_k(const int* __restrict__ srcv, const int* __restrict__ dstv,
            int* __restrict__ cursor, int* __restrict__ csr)
{
    int e = blockIdx.x * 256 + threadIdx.x;
    if (e < NE) {
        int pos = atomicAdd(&cursor[dstv[e]], 1);
        csr[pos] = srcv[e];
    }
}

// ---------------- weight prepass: transpose + bf16 ----------------
// WT1 [192][128]: rows 0-95 = w1_rel^T, 96-191 = w1_root^T
// WT2 [128][96] : rows 0-63 = w2_rel^T, 64-127 = w2_root^T
// WT3 [64][64]  : rows 0-31 = w_mu^T,   32-63  = w_ls^T
__global__ __launch_bounds__(256)
void wprep_k(const float* __restrict__ w1_rel, const float* __restrict__ w1_root,
             const float* __restrict__ w2_rel, const float* __restrict__ w2_root,
             const float* __restrict__ w_mu,   const float* __restrict__ w_ls,
             unsigned short* __restrict__ wt1, unsigned short* __restrict__ wt2,
             unsigned short* __restrict__ wt3)
{
    int i = blockIdx.x * 256 + threadIdx.x;
    if (i < 24576) {                       // WT1: K=128, N=192
        int k = i / 192, n = i % 192;
        float v = (n < 96) ? w1_rel[k * 96 + n] : w1_root[k * 96 + (n - 96)];
        wt1[n * 128 + k] = f2bf(v);
    } else if (i < 36864) {                // WT2: K=96, N=128
        int j = i - 24576;
        int k = j / 128, n = j % 128;
        float v = (n < 64) ? w2_rel[k * 64 + n] : w2_root[k * 64 + (n - 64)];
        wt2[n * 96 + k] = f2bf(v);
    } else if (i < 40960) {                // WT3: K=64, N=64
        int j = i - 36864;
        int k = j / 64, n = j % 64;
        float v = (n < 32) ? w_mu[k * 32 + n] : w_ls[k * 32 + (n - 32)];
        wt3[n * 64 + k] = f2bf(v);
    }
}

// ---------------- MFMA GEMM ----------------
// Block: 256 thr / 4 waves, M-tile = 128 nodes, NH output cols per y-slice.
// blockIdx.y selects output half: y=0 -> out0 (no bias), y=1 -> out1 (+bias).
// WT is [2*NH or NH][K] bf16 (k-contiguous); slice offset y*NH*K.
// LDS: A rows 0..127, B rows 128..128+NH-1, pitch K*2 bytes, XOR-swizzled
// (byte ^= (row&7)<<4) so ds_read_b128 fragment loads are min-conflict (G4).
template<int K, int NH, bool XB, bool SCALE>
__global__ __launch_bounds__(256)
void gemm_mfma(const void* __restrict__ Xv,
               const unsigned short* __restrict__ WT,
               const float* __restrict__ biasB,
               const float* __restrict__ scale,
               unsigned short* __restrict__ out0,
               unsigned short* __restrict__ out1)
{
    constexpr int KQ = K / 4;      // 4-element chunks per row
    constexpr int PB = K * 2;      // LDS row pitch (bytes)
    constexpr int KS = K / 32;     // mfma k-steps
    constexpr int NT = NH / 16;    // n-tiles
    __shared__ short lds[(128 + NH) * K];
    char* ldsb = (char*)lds;
    const int tid = threadIdx.x;
    const int blk = blockIdx.x;
    const int half = blockIdx.y;

    const unsigned short* wt = WT + (size_t)half * NH * K;
    unsigned short* outp = half ? out1 : out0;

    // ---- stage A (coalesced: lanes along K) ----
    #pragma unroll
    for (int it = 0; it < KQ / 2; ++it) {
        int idx = it * 256 + tid;
        int r = idx / KQ, c4 = idx % KQ;
        int node = blk * 128 + r; if (node >= NN) node = NN - 1;
        uint2 p;
        if (XB) {
            p = *(const uint2*)((const unsigned short*)Xv + (size_t)node * K + c4 * 4);
        } else {
            float4 v = *(const float4*)((const float*)Xv + (size_t)node * K + c4 * 4);
            p.x = packbf(v.x, v.y); p.y = packbf(v.z, v.w);
        }
        unsigned byte = (unsigned)(r * PB + c4 * 8) ^ ((unsigned)(r & 7) << 4);
        *(uint2*)(ldsb + byte) = p;
    }
    // ---- stage B ----
    #pragma unroll
    for (int it = 0; it < NH * KQ / 256; ++it) {
        int idx = it * 256 + tid;
        int n = idx / KQ, c4 = idx % KQ;
        uint2 p = *(const uint2*)(wt + (size_t)n * K + c4 * 4);
        int pr = 128 + n;
        unsigned byte = (unsigned)(pr * PB + c4 * 8) ^ ((unsigned)(pr & 7) << 4);
        *(uint2*)(ldsb + byte) = p;
    }
    __syncthreads();

    const int wv = tid >> 6, lane = tid & 63;
    const int r15 = lane & 15, g = lane >> 4;

    // A fragments for this wave's 32 rows (2 sub-tiles of 16), all k-steps.
    s16x8 afr[2][KS];
    #pragma unroll
    for (int ms = 0; ms < 2; ++ms) {
        #pragma unroll
        for (int ks = 0; ks < KS; ++ks) {
            int r = wv * 32 + ms * 16 + r15;
            unsigned byte = (unsigned)(r * PB + ks * 64 + g * 16) ^ ((unsigned)(r & 7) << 4);
            afr[ms][ks] = *(const s16x8*)(ldsb + byte);
        }
    }

    #pragma unroll
    for (int nt = 0; nt < NT; ++nt) {
        s16x8 bfr[KS];
        #pragma unroll
        for (int ks = 0; ks < KS; ++ks) {
            int pr = 128 + nt * 16 + r15;
            unsigned byte = (unsigned)(pr * PB + ks * 64 + g * 16) ^ ((unsigned)(pr & 7) << 4);
            bfr[ks] = *(const s16x8*)(ldsb + byte);
        }
        int c = nt * 16 + r15;
        float bias = (half && biasB) ? biasB[c] : 0.f;
        #pragma unroll
        for (int ms = 0; ms < 2; ++ms) {
            f32x4 acc = {0.f, 0.f, 0.f, 0.f};
            #pragma unroll
            for (int ks = 0; ks < KS; ++ks)
                acc = __builtin_amdgcn_mfma_f32_16x16x32_bf16(afr[ms][ks], bfr[ks], acc, 0, 0, 0);
            int nb = blk * 128 + wv * 32 + ms * 16 + g * 4;
            #pragma unroll
            for (int rg = 0; rg < 4; ++rg) {
                int node = nb + rg;
                if (node < NN) {
                    float v = acc[rg] + bias;
                    if (SCALE) v *= scale[node];
                    outp[(size_t)node * NH + c] = f2bf(v);
                }
            }
        }
    }
}

// ---------------- gather + relu (bf16, f32 accumulate) ----------------
template<int OC>
__global__ __launch_bounds__(256)
void gather_relu_k(const int* __restrict__ row_start,
                   const int* __restrict__ csr,
                   const unsigned short* __restrict__ msg,
                   unsigned short* __restrict__ hio)
{
    constexpr int G = OC / 8;
    int idx = blockIdx.x * 256 + threadIdx.x;
    if (idx >= NN * G) return;
    int i  = idx / G;
    int c8 = (idx - i * G) * 8;
    const size_t ro = (size_t)i * OC + c8;
    float a[8];
    {
        uint4 h = *(const uint4*)&hio[ro];
        a[0] = lof(h.x); a[1] = hif(h.x); a[2] = lof(h.y); a[3] = hif(h.y);
        a[4] = lof(h.z); a[5] = hif(h.z); a[6] = lof(h.w); a[7] = hif(h.w);
    }
    int e0 = row_start[i], e1 = row_start[i + 1];
    for (int e = e0; e < e1; ++e) {
        int s = csr[e];
        uint4 v = *(const uint4*)&msg[(size_t)s * OC + c8];
        a[0] += lof(v.x); a[1] += hif(v.x); a[2] += lof(v.y); a[3] += hif(v.y);
        a[4] += lof(v.z); a[5] += hif(v.z); a[6] += lof(v.w); a[7] += hif(v.w);
    }
    uint4 o;
    o.x = packbf(fmaxf(a[0], 0.f), fmaxf(a[1], 0.f));
    o.y = packbf(fmaxf(a[2], 0.f), fmaxf(a[3], 0.f));
    o.z = packbf(fmaxf(a[4], 0.f), fmaxf(a[5], 0.f));
    o.w = packbf(fmaxf(a[6], 0.f), fmaxf(a[7], 0.f));
    *(uint4*)&hio[ro] = o;
}

// ---------------- GCN gather: out = dinv_i*(y_i + sum y_j) + bias ----------------
__global__ __launch_bounds__(256)
void gather_gcn_k(const int* __restrict__ row_start,
                  const int* __restrict__ csr,
                  const unsigned short* __restrict__ y,   // bf16, pre-scaled by dinv
                  const float* __restrict__ dinv,
                  const float* __restrict__ b_mu,
                  const float* __restrict__ b_ls,
                  float* __restrict__ out)
{
    int idx = blockIdx.x * 256 + threadIdx.x;
    if (idx >= NN * 8) return;
    int i  = idx >> 3;
    int c8 = (idx & 7) * 8;
    float a[8];
    {
        uint4 h = *(const uint4*)&y[(size_t)i * 64 + c8];
        a[0] = lof(h.x); a[1] = hif(h.x); a[2] = lof(h.y); a[3] = hif(h.y);
        a[4] = lof(h.z); a[5] = hif(h.z); a[6] = lof(h.w); a[7] = hif(h.w);
    }
    int e0 = row_start[i], e1 = row_start[i + 1];
    for (int e = e0; e < e1; ++e) {
        int s = csr[e];
        uint4 v = *(const uint4*)&y[(size_t)s * 64 + c8];
        a[0] += lof(v.x); a[1] += hif(v.x); a[2] += lof(v.y); a[3] += hif(v.y);
        a[4] += lof(v.z); a[5] += hif(v.z); a[6] += lof(v.w); a[7] += hif(v.w);
    }
    float di = dinv[i];
    const float* b;
    float* o;
    if (c8 < 32) { b = &b_mu[c8];      o = &out[(size_t)i * 32 + c8]; }
    else         { b = &b_ls[c8 - 32]; o = &out[(size_t)NN * 32 + (size_t)i * 32 + (c8 - 32)]; }
    float4 r0, r1;
    r0.x = di * a[0] + b[0]; r0.y = di * a[1] + b[1];
    r0.z = di * a[2] + b[2]; r0.w = di * a[3] + b[3];
    r1.x = di * a[4] + b[4]; r1.y = di * a[5] + b[5];
    r1.z = di * a[6] + b[6]; r1.w = di * a[7] + b[7];
    *(float4*)&o[0] = r0;
    *(float4*)&o[4] = r1;
}

extern "C" void kernel_launch(void* const* d_in, const int* in_sizes, int n_in,
                              void* d_out, int out_size, void* d_ws, size_t ws_size,
                              hipStream_t stream)
{
    (void)in_sizes; (void)n_in; (void)out_size; (void)ws_size;
    const float* x       = (const float*)d_in[0];
    const int*   ei      = (const int*)d_in[1];
    const int*   srcv    = ei;
    const int*   dstv    = ei + NE;
    const float* w1_rel  = (const float*)d_in[2];
    const float* w1_root = (const float*)d_in[3];
    const float* b1      = (const float*)d_in[4];
    const float* w2_rel  = (const float*)d_in[5];
    const float* w2_root = (const float*)d_in[6];
    const float* b2      = (const float*)d_in[7];
    const float* w_mu    = (const float*)d_in[8];
    const float* b_mu    = (const float*)d_in[9];
    const float* w_ls    = (const float*)d_in[10];
    const float* b_ls    = (const float*)d_in[11];
    float* out = (float*)d_out;

    char* ws = (char*)d_ws;
    unsigned short* t1 = (unsigned short*)(ws);              // 9.6MB  NN*96 bf16
    unsigned short* h1 = (unsigned short*)(ws + 9600000);    // 9.6MB
    unsigned short* t2 = (unsigned short*)(ws + 19200000);   // 6.4MB  NN*64 bf16
    unsigned short* h2 = (unsigned short*)(ws + 25600000);   // 6.4MB
    unsigned short* y  = (unsigned short*)(ws + 32000000);   // 6.4MB
    int* csr       = (int*)(ws + 38400000);                  // 2.4MB
    int* row_start = (int*)(ws + 40800000);                  // (NN+1)*4
    int* cursor    = (int*)(ws + 41000016);                  // NN*4
    float* dinv    = (float*)(ws + 41200016);                // NN*4
    int* deg       = (int*)(ws + 41400016);                  // NN*4
    int* partial   = (int*)(ws + 41600016);                  // NB*4
    unsigned short* wt1 = (unsigned short*)(ws + 41700016);  // 192*128*2 = 49152
    unsigned short* wt2 = (unsigned short*)(ws + 41749168);  // 128*96*2  = 24576
    unsigned short* wt3 = (unsigned short*)(ws + 41773744);  // 64*64*2   = 8192

    // ---- CSR build + norm + weight prep ----
    hipMemsetAsync(deg, 0, NN * sizeof(int), stream);
    wprep_k<<<160, 256, 0, stream>>>(w1_rel, w1_root, w2_rel, w2_root, w_mu, w_ls,
                                     wt1, wt2, wt3);
    count_deg_k<<<(NE + 255) / 256, 256, 0, stream>>>(dstv, deg);
    scan_reduce_k<<<NB, 256, 0, stream>>>(deg, partial);
    scan_partials_k<<<1, 256, 0, stream>>>(partial, row_start);
    scan_final_k<<<NB, 256, 0, stream>>>(deg, partial, row_start, cursor, dinv);
    fill_k<<<(NE + 255) / 256, 256, 0, stream>>>(srcv, dstv, cursor, csr);

    const int NGB = (NN + 127) / 128;   // 391 M-tiles

    // ---- layer 1: t1 = x@w1_rel ; h1 = x@w1_root + b1 ----
    gemm_mfma<128, 96, false, false><<<dim3(NGB, 2), 256, 0, stream>>>(
        x, wt1, b1, nullptr, t1, h1);
    gather_relu_k<96><<<(NN * 12 + 255) / 256, 256, 0, stream>>>(row_start, csr, t1, h1);

    // ---- layer 2: t2 = h1@w2_rel ; h2 = h1@w2_root + b2 ----
    gemm_mfma<96, 64, true, false><<<dim3(NGB, 2), 256, 0, stream>>>(
        h1, wt2, b2, nullptr, t2, h2);
    gather_relu_k<64><<<(NN * 8 + 255) / 256, 256, 0, stream>>>(row_start, csr, t2, h2);

    // ---- layer 3: y = dinv * (h2 @ [w_mu | w_ls]) ----
    gemm_mfma<64, 64, true, true><<<dim3(NGB, 1), 256, 0, stream>>>(
        h2, wt3, nullptr, dinv, y, nullptr);
    gather_gcn_k<<<(NN * 8 + 255) / 256, 256, 0, stream>>>(row_start, csr, y, dinv, b_mu, b_ls, out);
}

// Round 6
// 178.551 us; speedup vs baseline: 10.7894x; 1.0715x over previous
//
#include <hip/hip_runtime.h>
#include <cstddef>

static constexpr int NN = 50000;
static constexpr int NE = 600000;
static constexpr int NB = (NN + 255) / 256;   // 196 scan blocks

using f32x4 = __attribute__((ext_vector_type(4))) float;
using s16x8 = __attribute__((ext_vector_type(8))) short;

// ---------------- bf16 helpers (manual, RNE) ----------------
__device__ inline float bf2f(unsigned short u) {
    return __uint_as_float(((unsigned)u) << 16);
}
__device__ inline unsigned short f2bf(float f) {
    unsigned u = __float_as_uint(f);
    unsigned r = u + 0x7fffu + ((u >> 16) & 1u);
    return (unsigned short)(r >> 16);
}
__device__ inline float lof(unsigned u) { return __uint_as_float(u << 16); }
__device__ inline float hif(unsigned u) { return __uint_as_float(u & 0xffff0000u); }
__device__ inline unsigned packbf(float a, float b) {
    return (unsigned)f2bf(a) | ((unsigned)f2bf(b) << 16);
}

// ---------------- zero deg (hipMemsetAsync's fill kernel took 41us!) --------
__global__ __launch_bounds__(256)
void zero_deg_k(int* __restrict__ deg) {
    int i = blockIdx.x * 256 + threadIdx.x;
    if (i < NN) deg[i] = 0;
}

// ---------------- degree count ----------------
__global__ __launch_bounds__(256)
void count_deg_k(const int* __restrict__ dstv, int* __restrict__ deg) {
    int e = blockIdx.x * 256 + threadIdx.x;
    if (e < NE) atomicAdd(&deg[dstv[e]], 1);
}

// ---------------- hierarchical scan ----------------
__global__ __launch_bounds__(256)
void scan_reduce_k(const int* __restrict__ deg, int* __restrict__ partial) {
    __shared__ int buf[256];
    int i = blockIdx.x * 256 + threadIdx.x;
    buf[threadIdx.x] = (i < NN) ? deg[i] : 0;
    __syncthreads();
    #pragma unroll
    for (int off = 128; off > 0; off >>= 1) {
        if (threadIdx.x < off) buf[threadIdx.x] += buf[threadIdx.x + off];
        __syncthreads();
    }
    if (threadIdx.x == 0) partial[blockIdx.x] = buf[0];
}

__global__ __launch_bounds__(256)
void scan_partials_k(int* __restrict__ partial, int* __restrict__ row_start) {
    __shared__ int buf[256];
    int t = threadIdx.x;
    int v = (t < NB) ? partial[t] : 0;
    buf[t] = v;
    __syncthreads();
    #pragma unroll
    for (int off = 1; off < 256; off <<= 1) {
        int tv = (t >= off) ? buf[t - off] : 0;
        __syncthreads();
        buf[t] += tv;
        __syncthreads();
    }
    if (t < NB) partial[t] = buf[t] - v;          // exclusive
    if (t == 255) row_start[NN] = buf[255];       // total == NE
}

__global__ __launch_bounds__(256)
void scan_final_k(const int* __restrict__ deg, const int* __restrict__ partial,
                  int* __restrict__ row_start, int* __restrict__ cursor,
                  float* __restrict__ dinv) {
    __shared__ int buf[256];
    int i = blockIdx.x * 256 + threadIdx.x;
    int t = threadIdx.x;
    int v = (i < NN) ? deg[i] : 0;
    buf[t] = v;
    __syncthreads();
    #pragma unroll
    for (int off = 1; off < 256; off <<= 1) {
        int tv = (t >= off) ? buf[t - off] : 0;
        __syncthreads();
        buf[t] += tv;
        __syncthreads();
    }
    if (i < NN) {
        int pos = partial[blockIdx.x] + buf[t] - v;
        row_start[i] = pos;
        cursor[i] = pos;
        dinv[i] = rsqrtf((float)v + 1.0f);        // +1 self-loop
    }
}

// ---------------- CSR fill ----------------
__global__ __launch_bounds__(256)
void fill_k(const int* __restrict__ srcv, const int* __restrict__ dstv,
            int* __restrict__ cursor, int* __restrict__ csr)
{
    int e = blockIdx.x * 256 + threadIdx.x;
    if (e < NE) {
        int pos = atomicAdd(&cursor[dstv[e]], 1);
        csr[pos] = srcv[e];
    }
}

// ---------------- weight prepass: transpose + bf16 ----------------
__global__ __launch_bounds__(256)
void wprep_k(const float* __restrict__ w1_rel, const float* __restrict__ w1_root,
             const float* __restrict__ w2_rel, const float* __restrict__ w2_root,
             const float* __restrict__ w_mu,   const float* __restrict__ w_ls,
             unsigned short* __restrict__ wt1, unsigned short* __restrict__ wt2,
             unsigned short* __restrict__ wt3)
{
    int i = blockIdx.x * 256 + threadIdx.x;
    if (i < 24576) {                       // WT1: K=128, N=192
        int k = i / 192, n = i % 192;
        float v = (n < 96) ? w1_rel[k * 96 + n] : w1_root[k * 96 + (n - 96)];
        wt1[n * 128 + k] = f2bf(v);
    } else if (i < 36864) {                // WT2: K=96, N=128
        int j = i - 24576;
        int k = j / 128, n = j % 128;
        float v = (n < 64) ? w2_rel[k * 64 + n] : w2_root[k * 64 + (n - 64)];
        wt2[n * 96 + k] = f2bf(v);
    } else if (i < 40960) {                // WT3: K=64, N=64
        int j = i - 36864;
        int k = j / 64, n = j % 64;
        float v = (n < 32) ? w_mu[k * 32 + n] : w_ls[k * 32 + (n - 32)];
        wt3[n * 64 + k] = f2bf(v);
    }
}

// ---------------- MFMA GEMM ----------------
template<int K, int NH, bool XB, bool SCALE>
__global__ __launch_bounds__(256)
void gemm_mfma(const void* __restrict__ Xv,
               const unsigned short* __restrict__ WT,
               const float* __restrict__ biasB,
               const float* __restrict__ scale,
               unsigned short* __restrict__ out0,
               unsigned short* __restrict__ out1)
{
    constexpr int KQ = K / 4;      // 4-element chunks per row
    constexpr int PB = K * 2;      // LDS row pitch (bytes)
    constexpr int KS = K / 32;     // mfma k-steps
    constexpr int NT = NH / 16;    // n-tiles
    __shared__ short lds[(128 + NH) * K];
    char* ldsb = (char*)lds;
    const int tid = threadIdx.x;
    const int blk = blockIdx.x;
    const int half = blockIdx.y;

    const unsigned short* wt = WT + (size_t)half * NH * K;
    unsigned short* outp = half ? out1 : out0;

    // ---- stage A (coalesced: lanes along K) ----
    #pragma unroll
    for (int it = 0; it < KQ / 2; ++it) {
        int idx = it * 256 + tid;
        int r = idx / KQ, c4 = idx % KQ;
        int node = blk * 128 + r; if (node >= NN) node = NN - 1;
        uint2 p;
        if (XB) {
            p = *(const uint2*)((const unsigned short*)Xv + (size_t)node * K + c4 * 4);
        } else {
            float4 v = *(const float4*)((const float*)Xv + (size_t)node * K + c4 * 4);
            p.x = packbf(v.x, v.y); p.y = packbf(v.z, v.w);
        }
        unsigned byte = (unsigned)(r * PB + c4 * 8) ^ ((unsigned)(r & 7) << 4);
        *(uint2*)(ldsb + byte) = p;
    }
    // ---- stage B ----
    #pragma unroll
    for (int it = 0; it < NH * KQ / 256; ++it) {
        int idx = it * 256 + tid;
        int n = idx / KQ, c4 = idx % KQ;
        uint2 p = *(const uint2*)(wt + (size_t)n * K + c4 * 4);
        int pr = 128 + n;
        unsigned byte = (unsigned)(pr * PB + c4 * 8) ^ ((unsigned)(pr & 7) << 4);
        *(uint2*)(ldsb + byte) = p;
    }
    __syncthreads();

    const int wv = tid >> 6, lane = tid & 63;
    const int r15 = lane & 15, g = lane >> 4;

    s16x8 afr[2][KS];
    #pragma unroll
    for (int ms = 0; ms < 2; ++ms) {
        #pragma unroll
        for (int ks = 0; ks < KS; ++ks) {
            int r = wv * 32 + ms * 16 + r15;
            unsigned byte = (unsigned)(r * PB + ks * 64 + g * 16) ^ ((unsigned)(r & 7) << 4);
            afr[ms][ks] = *(const s16x8*)(ldsb + byte);
        }
    }

    #pragma unroll
    for (int nt = 0; nt < NT; ++nt) {
        s16x8 bfr[KS];
        #pragma unroll
        for (int ks = 0; ks < KS; ++ks) {
            int pr = 128 + nt * 16 + r15;
            unsigned byte = (unsigned)(pr * PB + ks * 64 + g * 16) ^ ((unsigned)(pr & 7) << 4);
            bfr[ks] = *(const s16x8*)(ldsb + byte);
        }
        int c = nt * 16 + r15;
        float bias = (half && biasB) ? biasB[c] : 0.f;
        #pragma unroll
        for (int ms = 0; ms < 2; ++ms) {
            f32x4 acc = {0.f, 0.f, 0.f, 0.f};
            #pragma unroll
            for (int ks = 0; ks < KS; ++ks)
                acc = __builtin_amdgcn_mfma_f32_16x16x32_bf16(afr[ms][ks], bfr[ks], acc, 0, 0, 0);
            int nb = blk * 128 + wv * 32 + ms * 16 + g * 4;
            #pragma unroll
            for (int rg = 0; rg < 4; ++rg) {
                int node = nb + rg;
                if (node < NN) {
                    float v = acc[rg] + bias;
                    if (SCALE) v *= scale[node];
                    outp[(size_t)node * NH + c] = f2bf(v);
                }
            }
        }
    }
}

// ---------------- gather + relu (bf16, f32 accumulate, 2x unrolled) --------
template<int OC>
__global__ __launch_bounds__(256)
void gather_relu_k(const int* __restrict__ row_start,
                   const int* __restrict__ csr,
                   const unsigned short* __restrict__ msg,
                   unsigned short* __restrict__ hio)
{
    constexpr int G = OC / 8;
    int idx = blockIdx.x * 256 + threadIdx.x;
    if (idx >= NN * G) return;
    int i  = idx / G;
    int c8 = (idx - i * G) * 8;
    const size_t ro = (size_t)i * OC + c8;
    float a[8];
    {
        uint4 h = *(const uint4*)&hio[ro];
        a[0] = lof(h.x); a[1] = hif(h.x); a[2] = lof(h.y); a[3] = hif(h.y);
        a[4] = lof(h.z); a[5] = hif(h.z); a[6] = lof(h.w); a[7] = hif(h.w);
    }
    int e0 = row_start[i], e1 = row_start[i + 1];
    int e = e0;
    for (; e + 2 <= e1; e += 2) {
        int s0 = csr[e], s1 = csr[e + 1];
        uint4 v0 = *(const uint4*)&msg[(size_t)s0 * OC + c8];
        uint4 v1 = *(const uint4*)&msg[(size_t)s1 * OC + c8];
        a[0] += lof(v0.x); a[1] += hif(v0.x); a[2] += lof(v0.y); a[3] += hif(v0.y);
        a[4] += lof(v0.z); a[5] += hif(v0.z); a[6] += lof(v0.w); a[7] += hif(v0.w);
        a[0] += lof(v1.x); a[1] += hif(v1.x); a[2] += lof(v1.y); a[3] += hif(v1.y);
        a[4] += lof(v1.z); a[5] += hif(v1.z); a[6] += lof(v1.w); a[7] += hif(v1.w);
    }
    if (e < e1) {
        int s = csr[e];
        uint4 v = *(const uint4*)&msg[(size_t)s * OC + c8];
        a[0] += lof(v.x); a[1] += hif(v.x); a[2] += lof(v.y); a[3] += hif(v.y);
        a[4] += lof(v.z); a[5] += hif(v.z); a[6] += lof(v.w); a[7] += hif(v.w);
    }
    uint4 o;
    o.x = packbf(fmaxf(a[0], 0.f), fmaxf(a[1], 0.f));
    o.y = packbf(fmaxf(a[2], 0.f), fmaxf(a[3], 0.f));
    o.z = packbf(fmaxf(a[4], 0.f), fmaxf(a[5], 0.f));
    o.w = packbf(fmaxf(a[6], 0.f), fmaxf(a[7], 0.f));
    *(uint4*)&hio[ro] = o;
}

// ---------------- GCN gather: out = dinv_i*(y_i + sum y_j) + bias ----------
__global__ __launch_bounds__(256)
void gather_gcn_k(const int* __restrict__ row_start,
                  const int* __restrict__ csr,
                  const unsigned short* __restrict__ y,   // bf16, pre-scaled by dinv
                  const float* __restrict__ dinv,
                  const float* __restrict__ b_mu,
                  const float* __restrict__ b_ls,
                  float* __restrict__ out)
{
    int idx = blockIdx.x * 256 + threadIdx.x;
    if (idx >= NN * 8) return;
    int i  = idx >> 3;
    int c8 = (idx & 7) * 8;
    float a[8];
    {
        uint4 h = *(const uint4*)&y[(size_t)i * 64 + c8];
        a[0] = lof(h.x); a[1] = hif(h.x); a[2] = lof(h.y); a[3] = hif(h.y);
        a[4] = lof(h.z); a[5] = hif(h.z); a[6] = lof(h.w); a[7] = hif(h.w);
    }
    int e0 = row_start[i], e1 = row_start[i + 1];
    int e = e0;
    for (; e + 2 <= e1; e += 2) {
        int s0 = csr[e], s1 = csr[e + 1];
        uint4 v0 = *(const uint4*)&y[(size_t)s0 * 64 + c8];
        uint4 v1 = *(const uint4*)&y[(size_t)s1 * 64 + c8];
        a[0] += lof(v0.x); a[1] += hif(v0.x); a[2] += lof(v0.y); a[3] += hif(v0.y);
        a[4] += lof(v0.z); a[5] += hif(v0.z); a[6] += lof(v0.w); a[7] += hif(v0.w);
        a[0] += lof(v1.x); a[1] += hif(v1.x); a[2] += lof(v1.y); a[3] += hif(v1.y);
        a[4] += lof(v1.z); a[5] += hif(v1.z); a[6] += lof(v1.w); a[7] += hif(v1.w);
    }
    if (e < e1) {
        int s = csr[e];
        uint4 v = *(const uint4*)&y[(size_t)s * 64 + c8];
        a[0] += lof(v.x); a[1] += hif(v.x); a[2] += lof(v.y); a[3] += hif(v.y);
        a[4] += lof(v.z); a[5] += hif(v.z); a[6] += lof(v.w); a[7] += hif(v.w);
    }
    float di = dinv[i];
    const float* b;
    float* o;
    if (c8 < 32) { b = &b_mu[c8];      o = &out[(size_t)i * 32 + c8]; }
    else         { b = &b_ls[c8 - 32]; o = &out[(size_t)NN * 32 + (size_t)i * 32 + (c8 - 32)]; }
    float4 r0, r1;
    r0.x = di * a[0] + b[0]; r0.y = di * a[1] + b[1];
    r0.z = di * a[2] + b[2]; r0.w = di * a[3] + b[3];
    r1.x = di * a[4] + b[4]; r1.y = di * a[5] + b[5];
    r1.z = di * a[6] + b[6]; r1.w = di * a[7] + b[7];
    *(float4*)&o[0] = r0;
    *(float4*)&o[4] = r1;
}

extern "C" void kernel_launch(void* const* d_in, const int* in_sizes, int n_in,
                              void* d_out, int out_size, void* d_ws, size_t ws_size,
                              hipStream_t stream)
{
    (void)in_sizes; (void)n_in; (void)out_size; (void)ws_size;
    const float* x       = (const float*)d_in[0];
    const int*   ei      = (const int*)d_in[1];
    const int*   srcv    = ei;
    const int*   dstv    = ei + NE;
    const float* w1_rel  = (const float*)d_in[2];
    const float* w1_root = (const float*)d_in[3];
    const float* b1      = (const float*)d_in[4];
    const float* w2_rel  = (const float*)d_in[5];
    const float* w2_root = (const float*)d_in[6];
    const float* b2      = (const float*)d_in[7];
    const float* w_mu    = (const float*)d_in[8];
    const float* b_mu    = (const float*)d_in[9];
    const float* w_ls    = (const float*)d_in[10];
    const float* b_ls    = (const float*)d_in[11];
    float* out = (float*)d_out;

    char* ws = (char*)d_ws;
    unsigned short* t1 = (unsigned short*)(ws);              // 9.6MB  NN*96 bf16
    unsigned short* h1 = (unsigned short*)(ws + 9600000);    // 9.6MB
    unsigned short* t2 = (unsigned short*)(ws + 19200000);   // 6.4MB  NN*64 bf16
    unsigned short* h2 = (unsigned short*)(ws + 25600000);   // 6.4MB
    unsigned short* y  = (unsigned short*)(ws + 32000000);   // 6.4MB
    int* csr       = (int*)(ws + 38400000);                  // 2.4MB
    int* row_start = (int*)(ws + 40800000);                  // (NN+1)*4
    int* cursor    = (int*)(ws + 41000016);                  // NN*4
    float* dinv    = (float*)(ws + 41200016);                // NN*4
    int* deg       = (int*)(ws + 41400016);                  // NN*4
    int* partial   = (int*)(ws + 41600016);                  // NB*4
    unsigned short* wt1 = (unsigned short*)(ws + 41700016);  // 192*128*2
    unsigned short* wt2 = (unsigned short*)(ws + 41749168);  // 128*96*2
    unsigned short* wt3 = (unsigned short*)(ws + 41773744);  // 64*64*2

    // ---- CSR build + norm + weight prep ----
    zero_deg_k<<<NB, 256, 0, stream>>>(deg);
    wprep_k<<<160, 256, 0, stream>>>(w1_rel, w1_root, w2_rel, w2_root, w_mu, w_ls,
                                     wt1, wt2, wt3);
    count_deg_k<<<(NE + 255) / 256, 256, 0, stream>>>(dstv, deg);
    scan_reduce_k<<<NB, 256, 0, stream>>>(deg, partial);
    scan_partials_k<<<1, 256, 0, stream>>>(partial, row_start);
    scan_final_k<<<NB, 256, 0, stream>>>(deg, partial, row_start, cursor, dinv);
    fill_k<<<(NE + 255) / 256, 256, 0, stream>>>(srcv, dstv, cursor, csr);

    const int NGB = (NN + 127) / 128;   // 391 M-tiles

    // ---- layer 1: t1 = x@w1_rel ; h1 = x@w1_root + b1 ----
    gemm_mfma<128, 96, false, false><<<dim3(NGB, 2), 256, 0, stream>>>(
        x, wt1, b1, nullptr, t1, h1);
    gather_relu_k<96><<<(NN * 12 + 255) / 256, 256, 0, stream>>>(row_start, csr, t1, h1);

    // ---- layer 2: t2 = h1@w2_rel ; h2 = h1@w2_root + b2 ----
    gemm_mfma<96, 64, true, false><<<dim3(NGB, 2), 256, 0, stream>>>(
        h1, wt2, b2, nullptr, t2, h2);
    gather_relu_k<64><<<(NN * 8 + 255) / 256, 256, 0, stream>>>(row_start, csr, t2, h2);

    // ---- layer 3: y = dinv * (h2 @ [w_mu | w_ls]) ----
    gemm_mfma<64, 64, true, true><<<dim3(NGB, 1), 256, 0, stream>>>(
        h2, wt3, nullptr, dinv, y, nullptr);
    gather_gcn_k<<<(NN * 8 + 255) / 256, 256, 0, stream>>>(row_start, csr, y, dinv, b_mu, b_ls, out);
}

// Round 7
// 172.320 us; speedup vs baseline: 11.1795x; 1.0362x over previous
//
#include <hip/hip_runtime.h>
#include <cstddef>

static constexpr int NN = 50000;
static constexpr int NE = 600000;
static constexpr int NB = (NN + 255) / 256;   // 196 scan blocks

using f32x4 = __attribute__((ext_vector_type(4))) float;
using s16x8 = __attribute__((ext_vector_type(8))) short;

// ---------------- bf16 helpers (manual, RNE) ----------------
__device__ inline float bf2f(unsigned short u) {
    return __uint_as_float(((unsigned)u) << 16);
}
__device__ inline unsigned short f2bf(float f) {
    unsigned u = __float_as_uint(f);
    unsigned r = u + 0x7fffu + ((u >> 16) & 1u);
    return (unsigned short)(r >> 16);
}
__device__ inline float lof(unsigned u) { return __uint_as_float(u << 16); }
__device__ inline float hif(unsigned u) { return __uint_as_float(u & 0xffff0000u); }
__device__ inline unsigned packbf(float a, float b) {
    return (unsigned)f2bf(a) | ((unsigned)f2bf(b) << 16);
}

// ---------------- zero deg + weight transpose/bf16 prepass (fused) ----------
// WT1 [192][128]: rows 0-95 = w1_rel^T, 96-191 = w1_root^T
// WT2 [128][96] : rows 0-63 = w2_rel^T, 64-127 = w2_root^T
// WT3 [64][64]  : rows 0-31 = w_mu^T,   32-63  = w_ls^T
__global__ __launch_bounds__(256)
void zero_wprep_k(int* __restrict__ deg,
                  const float* __restrict__ w1_rel, const float* __restrict__ w1_root,
                  const float* __restrict__ w2_rel, const float* __restrict__ w2_root,
                  const float* __restrict__ w_mu,   const float* __restrict__ w_ls,
                  unsigned short* __restrict__ wt1, unsigned short* __restrict__ wt2,
                  unsigned short* __restrict__ wt3)
{
    int i = blockIdx.x * 256 + threadIdx.x;
    if (i < NN) deg[i] = 0;
    if (i < 24576) {                       // WT1: K=128, N=192
        int k = i / 192, n = i % 192;
        float v = (n < 96) ? w1_rel[k * 96 + n] : w1_root[k * 96 + (n - 96)];
        wt1[n * 128 + k] = f2bf(v);
    } else if (i < 36864) {                // WT2: K=96, N=128
        int j = i - 24576;
        int k = j / 128, n = j % 128;
        float v = (n < 64) ? w2_rel[k * 64 + n] : w2_root[k * 64 + (n - 64)];
        wt2[n * 96 + k] = f2bf(v);
    } else if (i < 40960) {                // WT3: K=64, N=64
        int j = i - 36864;
        int k = j / 64, n = j % 64;
        float v = (n < 32) ? w_mu[k * 32 + n] : w_ls[k * 32 + (n - 32)];
        wt3[n * 64 + k] = f2bf(v);
    }
}

// ---------------- degree count ----------------
__global__ __launch_bounds__(256)
void count_deg_k(const int* __restrict__ dstv, int* __restrict__ deg) {
    int e = blockIdx.x * 256 + threadIdx.x;
    if (e < NE) atomicAdd(&deg[dstv[e]], 1);
}

// ---------------- scan: per-block reduce -> partial ----------------
__global__ __launch_bounds__(256)
void scan_reduce_k(const int* __restrict__ deg, int* __restrict__ partial) {
    __shared__ int buf[256];
    int i = blockIdx.x * 256 + threadIdx.x;
    buf[threadIdx.x] = (i < NN) ? deg[i] : 0;
    __syncthreads();
    #pragma unroll
    for (int off = 128; off > 0; off >>= 1) {
        if (threadIdx.x < off) buf[threadIdx.x] += buf[threadIdx.x + off];
        __syncthreads();
    }
    if (threadIdx.x == 0) partial[blockIdx.x] = buf[0];
}

// ---------------- scan final: each block scans partials itself ----------------
__global__ __launch_bounds__(256)
void scan_final2_k(const int* __restrict__ deg, const int* __restrict__ partial,
                   int* __restrict__ row_start, int* __restrict__ cursor,
                   float* __restrict__ dinv) {
    __shared__ int pb[256], po[256], buf[256];
    int t = threadIdx.x;
    int pv = (t < NB) ? partial[t] : 0;
    pb[t] = pv; po[t] = pv;
    __syncthreads();
    #pragma unroll
    for (int off = 1; off < 256; off <<= 1) {
        int tv = (t >= off) ? pb[t - off] : 0;
        __syncthreads();
        pb[t] += tv;
        __syncthreads();
    }
    int i = blockIdx.x * 256 + t;
    int v = (i < NN) ? deg[i] : 0;
    buf[t] = v;
    __syncthreads();
    #pragma unroll
    for (int off = 1; off < 256; off <<= 1) {
        int tv = (t >= off) ? buf[t - off] : 0;
        __syncthreads();
        buf[t] += tv;
        __syncthreads();
    }
    int blkoff = pb[blockIdx.x] - po[blockIdx.x];   // exclusive offset of this block
    if (i < NN) {
        int pos = blkoff + buf[t] - v;
        row_start[i] = pos;
        cursor[i] = pos;
        dinv[i] = rsqrtf((float)v + 1.0f);          // +1 self-loop
    }
    if (blockIdx.x == 0 && t == 0) row_start[NN] = pb[NB - 1];   // == NE
}

// ---------------- CSR fill ----------------
__global__ __launch_bounds__(256)
void fill_k(const int* __restrict__ srcv, const int* __restrict__ dstv,
            int* __restrict__ cursor, int* __restrict__ csr)
{
    int e = blockIdx.x * 256 + threadIdx.x;
    if (e < NE) {
        int pos = atomicAdd(&cursor[dstv[e]], 1);
        csr[pos] = srcv[e];
    }
}

// ---------------- MFMA GEMM (layer 1, dense input) ----------------
template<int K, int NH, bool XB, bool SCALE>
__global__ __launch_bounds__(256)
void gemm_mfma(const void* __restrict__ Xv,
               const unsigned short* __restrict__ WT,
               const float* __restrict__ biasB,
               const float* __restrict__ scale,
               unsigned short* __restrict__ out0,
               unsigned short* __restrict__ out1)
{
    constexpr int KQ = K / 4;
    constexpr int PB = K * 2;
    constexpr int KS = K / 32;
    constexpr int NT = NH / 16;
    __shared__ short lds[(128 + NH) * K];
    char* ldsb = (char*)lds;
    const int tid = threadIdx.x;
    const int blk = blockIdx.x;
    const int half = blockIdx.y;

    const unsigned short* wt = WT + (size_t)half * NH * K;
    unsigned short* outp = half ? out1 : out0;

    #pragma unroll
    for (int it = 0; it < KQ / 2; ++it) {
        int idx = it * 256 + tid;
        int r = idx / KQ, c4 = idx % KQ;
        int node = blk * 128 + r; if (node >= NN) node = NN - 1;
        uint2 p;
        if (XB) {
            p = *(const uint2*)((const unsigned short*)Xv + (size_t)node * K + c4 * 4);
        } else {
            float4 v = *(const float4*)((const float*)Xv + (size_t)node * K + c4 * 4);
            p.x = packbf(v.x, v.y); p.y = packbf(v.z, v.w);
        }
        unsigned byte = (unsigned)(r * PB + c4 * 8) ^ ((unsigned)(r & 7) << 4);
        *(uint2*)(ldsb + byte) = p;
    }
    #pragma unroll
    for (int it = 0; it < NH * KQ / 256; ++it) {
        int idx = it * 256 + tid;
        int n = idx / KQ, c4 = idx % KQ;
        uint2 p = *(const uint2*)(wt + (size_t)n * K + c4 * 4);
        int pr = 128 + n;
        unsigned byte = (unsigned)(pr * PB + c4 * 8) ^ ((unsigned)(pr & 7) << 4);
        *(uint2*)(ldsb + byte) = p;
    }
    __syncthreads();

    const int wv = tid >> 6, lane = tid & 63;
    const int r15 = lane & 15, g = lane >> 4;

    s16x8 afr[2][KS];
    #pragma unroll
    for (int ms = 0; ms < 2; ++ms) {
        #pragma unroll
        for (int ks = 0; ks < KS; ++ks) {
            int r = wv * 32 + ms * 16 + r15;
            unsigned byte = (unsigned)(r * PB + ks * 64 + g * 16) ^ ((unsigned)(r & 7) << 4);
            afr[ms][ks] = *(const s16x8*)(ldsb + byte);
        }
    }

    #pragma unroll
    for (int nt = 0; nt < NT; ++nt) {
        s16x8 bfr[KS];
        #pragma unroll
        for (int ks = 0; ks < KS; ++ks) {
            int pr = 128 + nt * 16 + r15;
            unsigned byte = (unsigned)(pr * PB + ks * 64 + g * 16) ^ ((unsigned)(pr & 7) << 4);
            bfr[ks] = *(const s16x8*)(ldsb + byte);
        }
        int c = nt * 16 + r15;
        float bias = (half && biasB) ? biasB[c] : 0.f;
        #pragma unroll
        for (int ms = 0; ms < 2; ++ms) {
            f32x4 acc = {0.f, 0.f, 0.f, 0.f};
            #pragma unroll
            for (int ks = 0; ks < KS; ++ks)
                acc = __builtin_amdgcn_mfma_f32_16x16x32_bf16(afr[ms][ks], bfr[ks], acc, 0, 0, 0);
            int nb = blk * 128 + wv * 32 + ms * 16 + g * 4;
            #pragma unroll
            for (int rg = 0; rg < 4; ++rg) {
                int node = nb + rg;
                if (node < NN) {
                    float v = acc[rg] + bias;
                    if (SCALE) v *= scale[node];
                    outp[(size_t)node * NH + c] = f2bf(v);
                }
            }
        }
    }
}

// ---------------- fused gather+relu -> LDS A-tile -> MFMA GEMM ----------------
// M-tile = 64 nodes (782 blocks). Gather h = relu(hpre + sum msg[src]) straight
// into the swizzled LDS A-tile (bf16); h never touches global memory.
// SPLIT: cols < NHT/2 -> out0 ; cols >= NHT/2 -> out1 (+biasHi).
template<int K, int NHT, bool SPLIT, bool SCALE>
__global__ __launch_bounds__(256)
void gather_gemm_k(const int* __restrict__ row_start,
                   const int* __restrict__ csr,
                   const unsigned short* __restrict__ msg,   // [NN][K] bf16
                   const unsigned short* __restrict__ hpre,  // [NN][K] bf16
                   const unsigned short* __restrict__ WT,    // [NHT][K] bf16
                   const float* __restrict__ biasHi,
                   const float* __restrict__ scale,
                   unsigned short* __restrict__ out0,
                   unsigned short* __restrict__ out1)
{
    constexpr int G   = K / 8;
    constexpr int KQ  = K / 4;
    constexpr int PB  = K * 2;
    constexpr int KS  = K / 32;
    constexpr int NT  = NHT / 16;
    constexpr int NHh = NHT / 2;
    __shared__ short lds[(64 + NHT) * K];
    char* ldsb = (char*)lds;
    const int tid = threadIdx.x;
    const int blk = blockIdx.x;

    // ---- phase 1: gather+relu rows into LDS A-tile ----
    for (int w = tid; w < 64 * G; w += 256) {
        int r = w / G, ch = w - r * G;
        int c8 = ch * 8;
        int node = blk * 64 + r;
        float a[8] = {0.f,0.f,0.f,0.f,0.f,0.f,0.f,0.f};
        if (node < NN) {
            uint4 h = *(const uint4*)&hpre[(size_t)node * K + c8];
            a[0] = lof(h.x); a[1] = hif(h.x); a[2] = lof(h.y); a[3] = hif(h.y);
            a[4] = lof(h.z); a[5] = hif(h.z); a[6] = lof(h.w); a[7] = hif(h.w);
            int e0 = row_start[node], e1 = row_start[node + 1];
            int e = e0;
            for (; e + 2 <= e1; e += 2) {
                int s0 = csr[e], s1 = csr[e + 1];
                uint4 v0 = *(const uint4*)&msg[(size_t)s0 * K + c8];
                uint4 v1 = *(const uint4*)&msg[(size_t)s1 * K + c8];
                a[0] += lof(v0.x); a[1] += hif(v0.x); a[2] += lof(v0.y); a[3] += hif(v0.y);
                a[4] += lof(v0.z); a[5] += hif(v0.z); a[6] += lof(v0.w); a[7] += hif(v0.w);
                a[0] += lof(v1.x); a[1] += hif(v1.x); a[2] += lof(v1.y); a[3] += hif(v1.y);
                a[4] += lof(v1.z); a[5] += hif(v1.z); a[6] += lof(v1.w); a[7] += hif(v1.w);
            }
            if (e < e1) {
                int s = csr[e];
                uint4 v = *(const uint4*)&msg[(size_t)s * K + c8];
                a[0] += lof(v.x); a[1] += hif(v.x); a[2] += lof(v.y); a[3] += hif(v.y);
                a[4] += lof(v.z); a[5] += hif(v.z); a[6] += lof(v.w); a[7] += hif(v.w);
            }
            #pragma unroll
            for (int q = 0; q < 8; ++q) a[q] = fmaxf(a[q], 0.f);
        }
        uint4 o;
        o.x = packbf(a[0], a[1]); o.y = packbf(a[2], a[3]);
        o.z = packbf(a[4], a[5]); o.w = packbf(a[6], a[7]);
        unsigned byte = (unsigned)(r * PB + ch * 16) ^ ((unsigned)(r & 7) << 4);
        *(uint4*)(ldsb + byte) = o;
    }
    // ---- phase 1b: stage weights ----
    #pragma unroll
    for (int it = 0; it < NHT * KQ / 256; ++it) {
        int idx = it * 256 + tid;
        int n = idx / KQ, c4 = idx % KQ;
        uint2 p = *(const uint2*)(WT + (size_t)n * K + c4 * 4);
        int pr = 64 + n;
        unsigned byte = (unsigned)(pr * PB + c4 * 8) ^ ((unsigned)(pr & 7) << 4);
        *(uint2*)(ldsb + byte) = p;
    }
    __syncthreads();

    // ---- phase 2: MFMA. Wave wv owns rows wv*16..wv*16+15. ----
    const int wv = tid >> 6, lane = tid & 63;
    const int r15 = lane & 15, g = lane >> 4;

    s16x8 afr[KS];
    #pragma unroll
    for (int ks = 0; ks < KS; ++ks) {
        int r = wv * 16 + r15;
        unsigned byte = (unsigned)(r * PB + ks * 64 + g * 16) ^ ((unsigned)(r & 7) << 4);
        afr[ks] = *(const s16x8*)(ldsb + byte);
    }

    #pragma unroll
    for (int nt = 0; nt < NT; ++nt) {
        s16x8 bfr[KS];
        #pragma unroll
        for (int ks = 0; ks < KS; ++ks) {
            int pr = 64 + nt * 16 + r15;
            unsigned byte = (unsigned)(pr * PB + ks * 64 + g * 16) ^ ((unsigned)(pr & 7) << 4);
            bfr[ks] = *(const s16x8*)(ldsb + byte);
        }
        int c = nt * 16 + r15;
        float bias = 0.f;
        if (SPLIT && biasHi && c >= NHh) bias = biasHi[c - NHh];
        f32x4 acc = {0.f, 0.f, 0.f, 0.f};
        #pragma unroll
        for (int ks = 0; ks < KS; ++ks)
            acc = __builtin_amdgcn_mfma_f32_16x16x32_bf16(afr[ks], bfr[ks], acc, 0, 0, 0);
        int nb = blk * 64 + wv * 16 + g * 4;
        #pragma unroll
        for (int rg = 0; rg < 4; ++rg) {
            int node = nb + rg;
            if (node < NN) {
                float v = acc[rg] + bias;
                if (SCALE) v *= scale[node];
                if (SPLIT) {
                    if (c < NHh) out0[(size_t)node * NHh + c] = f2bf(v);
                    else         out1[(size_t)node * NHh + (c - NHh)] = f2bf(v);
                } else {
                    out0[(size_t)node * NHT + c] = f2bf(v);
                }
            }
        }
    }
}

// ---------------- GCN gather: out = dinv_i*(y_i + sum y_j) + bias ----------
__global__ __launch_bounds__(256)
void gather_gcn_k(const int* __restrict__ row_start,
                  const int* __restrict__ csr,
                  const unsigned short* __restrict__ y,   // bf16, pre-scaled by dinv
                  const float* __restrict__ dinv,
                  const float* __restrict__ b_mu,
                  const float* __restrict__ b_ls,
                  float* __restrict__ out)
{
    int idx = blockIdx.x * 256 + threadIdx.x;
    if (idx >= NN * 8) return;
    int i  = idx >> 3;
    int c8 = (idx & 7) * 8;
    float a[8];
    {
        uint4 h = *(const uint4*)&y[(size_t)i * 64 + c8];
        a[0] = lof(h.x); a[1] = hif(h.x); a[2] = lof(h.y); a[3] = hif(h.y);
        a[4] = lof(h.z); a[5] = hif(h.z); a[6] = lof(h.w); a[7] = hif(h.w);
    }
    int e0 = row_start[i], e1 = row_start[i + 1];
    int e = e0;
    for (; e + 2 <= e1; e += 2) {
        int s0 = csr[e], s1 = csr[e + 1];
        uint4 v0 = *(const uint4*)&y[(size_t)s0 * 64 + c8];
        uint4 v1 = *(const uint4*)&y[(size_t)s1 * 64 + c8];
        a[0] += lof(v0.x); a[1] += hif(v0.x); a[2] += lof(v0.y); a[3] += hif(v0.y);
        a[4] += lof(v0.z); a[5] += hif(v0.z); a[6] += lof(v0.w); a[7] += hif(v0.w);
        a[0] += lof(v1.x); a[1] += hif(v1.x); a[2] += lof(v1.y); a[3] += hif(v1.y);
        a[4] += lof(v1.z); a[5] += hif(v1.z); a[6] += lof(v1.w); a[7] += hif(v1.w);
    }
    if (e < e1) {
        int s = csr[e];
        uint4 v = *(const uint4*)&y[(size_t)s * 64 + c8];
        a[0] += lof(v.x); a[1] += hif(v.x); a[2] += lof(v.y); a[3] += hif(v.y);
        a[4] += lof(v.z); a[5] += hif(v.z); a[6] += lof(v.w); a[7] += hif(v.w);
    }
    float di = dinv[i];
    const float* b;
    float* o;
    if (c8 < 32) { b = &b_mu[c8];      o = &out[(size_t)i * 32 + c8]; }
    else         { b = &b_ls[c8 - 32]; o = &out[(size_t)NN * 32 + (size_t)i * 32 + (c8 - 32)]; }
    float4 r0, r1;
    r0.x = di * a[0] + b[0]; r0.y = di * a[1] + b[1];
    r0.z = di * a[2] + b[2]; r0.w = di * a[3] + b[3];
    r1.x = di * a[4] + b[4]; r1.y = di * a[5] + b[5];
    r1.z = di * a[6] + b[6]; r1.w = di * a[7] + b[7];
    *(float4*)&o[0] = r0;
    *(float4*)&o[4] = r1;
}

extern "C" void kernel_launch(void* const* d_in, const int* in_sizes, int n_in,
                              void* d_out, int out_size, void* d_ws, size_t ws_size,
                              hipStream_t stream)
{
    (void)in_sizes; (void)n_in; (void)out_size; (void)ws_size;
    const float* x       = (const float*)d_in[0];
    const int*   ei      = (const int*)d_in[1];
    const int*   srcv    = ei;
    const int*   dstv    = ei + NE;
    const float* w1_rel  = (const float*)d_in[2];
    const float* w1_root = (const float*)d_in[3];
    const float* b1      = (const float*)d_in[4];
    const float* w2_rel  = (const float*)d_in[5];
    const float* w2_root = (const float*)d_in[6];
    const float* b2      = (const float*)d_in[7];
    const float* w_mu    = (const float*)d_in[8];
    const float* b_mu    = (const float*)d_in[9];
    const float* w_ls    = (const float*)d_in[10];
    const float* b_ls    = (const float*)d_in[11];
    float* out = (float*)d_out;

    char* ws = (char*)d_ws;
    unsigned short* t1    = (unsigned short*)(ws);              // 9.6MB  NN*96 bf16
    unsigned short* h1pre = (unsigned short*)(ws + 9600000);    // 9.6MB
    unsigned short* t2    = (unsigned short*)(ws + 19200000);   // 6.4MB  NN*64 bf16
    unsigned short* h2pre = (unsigned short*)(ws + 25600000);   // 6.4MB
    unsigned short* y     = (unsigned short*)(ws + 32000000);   // 6.4MB
    int* csr       = (int*)(ws + 38400000);                     // 2.4MB
    int* row_start = (int*)(ws + 40800000);                     // (NN+1)*4
    int* cursor    = (int*)(ws + 41000016);                     // NN*4
    float* dinv    = (float*)(ws + 41200016);                   // NN*4
    int* deg       = (int*)(ws + 41400016);                     // NN*4
    int* partial   = (int*)(ws + 41600016);                     // NB*4
    unsigned short* wt1 = (unsigned short*)(ws + 41700016);     // 192*128*2
    unsigned short* wt2 = (unsigned short*)(ws + 41749168);     // 128*96*2
    unsigned short* wt3 = (unsigned short*)(ws + 41773744);     // 64*64*2

    // ---- CSR build + norm + weight prep (5 launches) ----
    zero_wprep_k<<<NB, 256, 0, stream>>>(deg, w1_rel, w1_root, w2_rel, w2_root,
                                         w_mu, w_ls, wt1, wt2, wt3);
    count_deg_k<<<(NE + 255) / 256, 256, 0, stream>>>(dstv, deg);
    scan_reduce_k<<<NB, 256, 0, stream>>>(deg, partial);
    scan_final2_k<<<NB, 256, 0, stream>>>(deg, partial, row_start, cursor, dinv);
    fill_k<<<(NE + 255) / 256, 256, 0, stream>>>(srcv, dstv, cursor, csr);

    // ---- layer 1: t1 = x@w1_rel ; h1pre = x@w1_root + b1 ----
    gemm_mfma<128, 96, false, false><<<dim3(391, 2), 256, 0, stream>>>(
        x, wt1, b1, nullptr, t1, h1pre);

    // ---- layer 2 (fused): h1 = relu(h1pre + gather t1) in LDS;
    //      t2 = h1@w2_rel ; h2pre = h1@w2_root + b2 ----
    gather_gemm_k<96, 128, true, false><<<782, 256, 0, stream>>>(
        row_start, csr, t1, h1pre, wt2, b2, nullptr, t2, h2pre);

    // ---- layer 3 (fused): h2 = relu(h2pre + gather t2) in LDS;
    //      y = dinv * (h2 @ [w_mu | w_ls]) ----
    gather_gemm_k<64, 64, false, true><<<782, 256, 0, stream>>>(
        row_start, csr, t2, h2pre, wt3, nullptr, dinv, y, nullptr);

    // ---- GCN aggregate + bias -> out ----
    gather_gcn_k<<<(NN * 8 + 255) / 256, 256, 0, stream>>>(row_start, csr, y, dinv, b_mu, b_ls, out);
}

// Round 8
// 158.062 us; speedup vs baseline: 12.1880x; 1.0902x over previous
//
#include <hip/hip_runtime.h>
#include <cstddef>

static constexpr int NN = 50000;
static constexpr int NE = 600000;
static constexpr int NB = (NN + 255) / 256;   // 196 scan blocks

using f32x4 = __attribute__((ext_vector_type(4))) float;
using s16x8 = __attribute__((ext_vector_type(8))) short;

// ---------------- bf16 helpers (manual, RNE) ----------------
__device__ inline float bf2f(unsigned short u) {
    return __uint_as_float(((unsigned)u) << 16);
}
__device__ inline unsigned short f2bf(float f) {
    unsigned u = __float_as_uint(f);
    unsigned r = u + 0x7fffu + ((u >> 16) & 1u);
    return (unsigned short)(r >> 16);
}
__device__ inline float lof(unsigned u) { return __uint_as_float(u << 16); }
__device__ inline float hif(unsigned u) { return __uint_as_float(u & 0xffff0000u); }
__device__ inline unsigned packbf(float a, float b) {
    return (unsigned)f2bf(a) | ((unsigned)f2bf(b) << 16);
}

// ---------------- zero deg + weight transpose/bf16 prepass (fused) ----------
__global__ __launch_bounds__(256)
void zero_wprep_k(int* __restrict__ deg,
                  const float* __restrict__ w1_rel, const float* __restrict__ w1_root,
                  const float* __restrict__ w2_rel, const float* __restrict__ w2_root,
                  const float* __restrict__ w_mu,   const float* __restrict__ w_ls,
                  unsigned short* __restrict__ wt1, unsigned short* __restrict__ wt2,
                  unsigned short* __restrict__ wt3)
{
    int i = blockIdx.x * 256 + threadIdx.x;
    if (i < NN) deg[i] = 0;
    if (i < 24576) {                       // WT1: K=128, N=192
        int k = i / 192, n = i % 192;
        float v = (n < 96) ? w1_rel[k * 96 + n] : w1_root[k * 96 + (n - 96)];
        wt1[n * 128 + k] = f2bf(v);
    } else if (i < 36864) {                // WT2: K=96, N=128
        int j = i - 24576;
        int k = j / 128, n = j % 128;
        float v = (n < 64) ? w2_rel[k * 64 + n] : w2_root[k * 64 + (n - 64)];
        wt2[n * 96 + k] = f2bf(v);
    } else if (i < 40960) {                // WT3: K=64, N=64
        int j = i - 36864;
        int k = j / 64, n = j % 64;
        float v = (n < 32) ? w_mu[k * 32 + n] : w_ls[k * 32 + (n - 32)];
        wt3[n * 64 + k] = f2bf(v);
    }
}

// ---------------- degree count ----------------
__global__ __launch_bounds__(256)
void count_deg_k(const int* __restrict__ dstv, int* __restrict__ deg) {
    int e = blockIdx.x * 256 + threadIdx.x;
    if (e < NE) atomicAdd(&deg[dstv[e]], 1);
}

// ---------------- scan: per-block reduce -> partial ----------------
__global__ __launch_bounds__(256)
void scan_reduce_k(const int* __restrict__ deg, int* __restrict__ partial) {
    __shared__ int buf[256];
    int i = blockIdx.x * 256 + threadIdx.x;
    buf[threadIdx.x] = (i < NN) ? deg[i] : 0;
    __syncthreads();
    #pragma unroll
    for (int off = 128; off > 0; off >>= 1) {
        if (threadIdx.x < off) buf[threadIdx.x] += buf[threadIdx.x + off];
        __syncthreads();
    }
    if (threadIdx.x == 0) partial[blockIdx.x] = buf[0];
}

// ---------------- scan final: each block scans partials itself ----------------
__global__ __launch_bounds__(256)
void scan_final2_k(const int* __restrict__ deg, const int* __restrict__ partial,
                   int* __restrict__ row_start, int* __restrict__ cursor,
                   float* __restrict__ dinv) {
    __shared__ int pb[256], po[256], buf[256];
    int t = threadIdx.x;
    int pv = (t < NB) ? partial[t] : 0;
    pb[t] = pv; po[t] = pv;
    __syncthreads();
    #pragma unroll
    for (int off = 1; off < 256; off <<= 1) {
        int tv = (t >= off) ? pb[t - off] : 0;
        __syncthreads();
        pb[t] += tv;
        __syncthreads();
    }
    int i = blockIdx.x * 256 + t;
    int v = (i < NN) ? deg[i] : 0;
    buf[t] = v;
    __syncthreads();
    #pragma unroll
    for (int off = 1; off < 256; off <<= 1) {
        int tv = (t >= off) ? buf[t - off] : 0;
        __syncthreads();
        buf[t] += tv;
        __syncthreads();
    }
    int blkoff = pb[blockIdx.x] - po[blockIdx.x];   // exclusive offset of this block
    if (i < NN) {
        int pos = blkoff + buf[t] - v;
        row_start[i] = pos;
        cursor[i] = pos;
        dinv[i] = rsqrtf((float)v + 1.0f);          // +1 self-loop
    }
    if (blockIdx.x == 0 && t == 0) row_start[NN] = pb[NB - 1];   // == NE
}

// ---------------- CSR fill ----------------
__global__ __launch_bounds__(256)
void fill_k(const int* __restrict__ srcv, const int* __restrict__ dstv,
            int* __restrict__ cursor, int* __restrict__ csr)
{
    int e = blockIdx.x * 256 + threadIdx.x;
    if (e < NE) {
        int pos = atomicAdd(&cursor[dstv[e]], 1);
        csr[pos] = srcv[e];
    }
}

// ---------------- MFMA GEMM (layer 1, dense input) ----------------
template<int K, int NH, bool XB, bool SCALE>
__global__ __launch_bounds__(256)
void gemm_mfma(const void* __restrict__ Xv,
               const unsigned short* __restrict__ WT,
               const float* __restrict__ biasB,
               const float* __restrict__ scale,
               unsigned short* __restrict__ out0,
               unsigned short* __restrict__ out1)
{
    constexpr int KQ = K / 4;
    constexpr int PB = K * 2;
    constexpr int KS = K / 32;
    constexpr int NT = NH / 16;
    __shared__ short lds[(128 + NH) * K];
    char* ldsb = (char*)lds;
    const int tid = threadIdx.x;
    const int blk = blockIdx.x;
    const int half = blockIdx.y;

    const unsigned short* wt = WT + (size_t)half * NH * K;
    unsigned short* outp = half ? out1 : out0;

    #pragma unroll
    for (int it = 0; it < KQ / 2; ++it) {
        int idx = it * 256 + tid;
        int r = idx / KQ, c4 = idx % KQ;
        int node = blk * 128 + r; if (node >= NN) node = NN - 1;
        uint2 p;
        if (XB) {
            p = *(const uint2*)((const unsigned short*)Xv + (size_t)node * K + c4 * 4);
        } else {
            float4 v = *(const float4*)((const float*)Xv + (size_t)node * K + c4 * 4);
            p.x = packbf(v.x, v.y); p.y = packbf(v.z, v.w);
        }
        unsigned byte = (unsigned)(r * PB + c4 * 8) ^ ((unsigned)(r & 7) << 4);
        *(uint2*)(ldsb + byte) = p;
    }
    #pragma unroll
    for (int it = 0; it < NH * KQ / 256; ++it) {
        int idx = it * 256 + tid;
        int n = idx / KQ, c4 = idx % KQ;
        uint2 p = *(const uint2*)(wt + (size_t)n * K + c4 * 4);
        int pr = 128 + n;
        unsigned byte = (unsigned)(pr * PB + c4 * 8) ^ ((unsigned)(pr & 7) << 4);
        *(uint2*)(ldsb + byte) = p;
    }
    __syncthreads();

    const int wv = tid >> 6, lane = tid & 63;
    const int r15 = lane & 15, g = lane >> 4;

    s16x8 afr[2][KS];
    #pragma unroll
    for (int ms = 0; ms < 2; ++ms) {
        #pragma unroll
        for (int ks = 0; ks < KS; ++ks) {
            int r = wv * 32 + ms * 16 + r15;
            unsigned byte = (unsigned)(r * PB + ks * 64 + g * 16) ^ ((unsigned)(r & 7) << 4);
            afr[ms][ks] = *(const s16x8*)(ldsb + byte);
        }
    }

    #pragma unroll
    for (int nt = 0; nt < NT; ++nt) {
        s16x8 bfr[KS];
        #pragma unroll
        for (int ks = 0; ks < KS; ++ks) {
            int pr = 128 + nt * 16 + r15;
            unsigned byte = (unsigned)(pr * PB + ks * 64 + g * 16) ^ ((unsigned)(pr & 7) << 4);
            bfr[ks] = *(const s16x8*)(ldsb + byte);
        }
        int c = nt * 16 + r15;
        float bias = (half && biasB) ? biasB[c] : 0.f;
        #pragma unroll
        for (int ms = 0; ms < 2; ++ms) {
            f32x4 acc = {0.f, 0.f, 0.f, 0.f};
            #pragma unroll
            for (int ks = 0; ks < KS; ++ks)
                acc = __builtin_amdgcn_mfma_f32_16x16x32_bf16(afr[ms][ks], bfr[ks], acc, 0, 0, 0);
            int nb = blk * 128 + wv * 32 + ms * 16 + g * 4;
            #pragma unroll
            for (int rg = 0; rg < 4; ++rg) {
                int node = nb + rg;
                if (node < NN) {
                    float v = acc[rg] + bias;
                    if (SCALE) v *= scale[node];
                    outp[(size_t)node * NH + c] = f2bf(v);
                }
            }
        }
    }
}

// ---------------- fused gather+relu -> LDS A-tile -> MFMA GEMM ----------------
// 512 threads / 8 waves. M-tile = 64 nodes (782 blocks).
// Edge-split-2: two adjacent lanes share one (row, chunk), covering even/odd
// edges; combined via __shfl_xor(.,1). Halves max-degree serialization and
// doubles loads-in-flight. MFMA phase: wave wv -> rows (wv>>1)*16, N-half wv&1.
template<int K, int NHT, bool SPLIT, bool SCALE>
__global__ __launch_bounds__(512)
void gather_gemm_k(const int* __restrict__ row_start,
                   const int* __restrict__ csr,
                   const unsigned short* __restrict__ msg,   // [NN][K] bf16
                   const unsigned short* __restrict__ hpre,  // [NN][K] bf16
                   const unsigned short* __restrict__ WT,    // [NHT][K] bf16
                   const float* __restrict__ biasHi,
                   const float* __restrict__ scale,
                   unsigned short* __restrict__ out0,
                   unsigned short* __restrict__ out1)
{
    constexpr int G   = K / 8;
    constexpr int G2  = G * 2;       // threads per row (edge-split-2)
    constexpr int KQ  = K / 4;
    constexpr int PB  = K * 2;
    constexpr int KS  = K / 32;
    constexpr int NT  = NHT / 16;
    constexpr int NTW = NT / 2;      // n-tiles per wave
    constexpr int NHh = NHT / 2;
    __shared__ short lds[(64 + NHT) * K];
    char* ldsb = (char*)lds;
    const int tid = threadIdx.x;
    const int blk = blockIdx.x;

    // ---- phase 1: gather+relu rows into LDS A-tile ----
    for (int it = 0; it < 64 * G2 / 512; ++it) {
        int w = it * 512 + tid;
        int r = w / G2;
        int rem = w - r * G2;
        int ch = rem >> 1, sub = rem & 1;
        int c8 = ch * 8;
        int node = blk * 64 + r;
        float a[8] = {0.f,0.f,0.f,0.f,0.f,0.f,0.f,0.f};
        if (node < NN) {
            if (sub == 0) {
                uint4 h = *(const uint4*)&hpre[(size_t)node * K + c8];
                a[0] = lof(h.x); a[1] = hif(h.x); a[2] = lof(h.y); a[3] = hif(h.y);
                a[4] = lof(h.z); a[5] = hif(h.z); a[6] = lof(h.w); a[7] = hif(h.w);
            }
            int e0 = row_start[node], e1 = row_start[node + 1];
            int e = e0 + sub;
            for (; e + 2 < e1; e += 4) {
                int s0 = csr[e], s1 = csr[e + 2];
                uint4 v0 = *(const uint4*)&msg[(size_t)s0 * K + c8];
                uint4 v1 = *(const uint4*)&msg[(size_t)s1 * K + c8];
                a[0] += lof(v0.x); a[1] += hif(v0.x); a[2] += lof(v0.y); a[3] += hif(v0.y);
                a[4] += lof(v0.z); a[5] += hif(v0.z); a[6] += lof(v0.w); a[7] += hif(v0.w);
                a[0] += lof(v1.x); a[1] += hif(v1.x); a[2] += lof(v1.y); a[3] += hif(v1.y);
                a[4] += lof(v1.z); a[5] += hif(v1.z); a[6] += lof(v1.w); a[7] += hif(v1.w);
            }
            if (e < e1) {
                int s = csr[e];
                uint4 v = *(const uint4*)&msg[(size_t)s * K + c8];
                a[0] += lof(v.x); a[1] += hif(v.x); a[2] += lof(v.y); a[3] += hif(v.y);
                a[4] += lof(v.z); a[5] += hif(v.z); a[6] += lof(v.w); a[7] += hif(v.w);
            }
        }
        #pragma unroll
        for (int q = 0; q < 8; ++q) {
            a[q] += __shfl_xor(a[q], 1);
            a[q] = fmaxf(a[q], 0.f);
        }
        if (sub == 0) {
            uint4 o;
            o.x = packbf(a[0], a[1]); o.y = packbf(a[2], a[3]);
            o.z = packbf(a[4], a[5]); o.w = packbf(a[6], a[7]);
            unsigned byte = (unsigned)(r * PB + ch * 16) ^ ((unsigned)(r & 7) << 4);
            *(uint4*)(ldsb + byte) = o;
        }
    }
    // ---- phase 1b: stage weights ----
    #pragma unroll
    for (int it = 0; it < NHT * KQ / 512; ++it) {
        int idx = it * 512 + tid;
        int n = idx / KQ, c4 = idx % KQ;
        uint2 p = *(const uint2*)(WT + (size_t)n * K + c4 * 4);
        int pr = 64 + n;
        unsigned byte = (unsigned)(pr * PB + c4 * 8) ^ ((unsigned)(pr & 7) << 4);
        *(uint2*)(ldsb + byte) = p;
    }
    __syncthreads();

    // ---- phase 2: MFMA. wave wv: rows (wv>>1)*16.. ; n-half wv&1 ----
    const int wv = tid >> 6, lane = tid & 63;
    const int r15 = lane & 15, g = lane >> 4;
    const int rt = wv >> 1, nth = wv & 1;

    s16x8 afr[KS];
    #pragma unroll
    for (int ks = 0; ks < KS; ++ks) {
        int r = rt * 16 + r15;
        unsigned byte = (unsigned)(r * PB + ks * 64 + g * 16) ^ ((unsigned)(r & 7) << 4);
        afr[ks] = *(const s16x8*)(ldsb + byte);
    }

    #pragma unroll
    for (int ntl = 0; ntl < NTW; ++ntl) {
        int nt = nth * NTW + ntl;
        s16x8 bfr[KS];
        #pragma unroll
        for (int ks = 0; ks < KS; ++ks) {
            int pr = 64 + nt * 16 + r15;
            unsigned byte = (unsigned)(pr * PB + ks * 64 + g * 16) ^ ((unsigned)(pr & 7) << 4);
            bfr[ks] = *(const s16x8*)(ldsb + byte);
        }
        int c = nt * 16 + r15;
        float bias = 0.f;
        if (SPLIT && biasHi && c >= NHh) bias = biasHi[c - NHh];
        f32x4 acc = {0.f, 0.f, 0.f, 0.f};
        #pragma unroll
        for (int ks = 0; ks < KS; ++ks)
            acc = __builtin_amdgcn_mfma_f32_16x16x32_bf16(afr[ks], bfr[ks], acc, 0, 0, 0);
        int nb = blk * 64 + rt * 16 + g * 4;
        #pragma unroll
        for (int rg = 0; rg < 4; ++rg) {
            int node = nb + rg;
            if (node < NN) {
                float v = acc[rg] + bias;
                if (SCALE) v *= scale[node];
                if (SPLIT) {
                    if (c < NHh) out0[(size_t)node * NHh + c] = f2bf(v);
                    else         out1[(size_t)node * NHh + (c - NHh)] = f2bf(v);
                } else {
                    out0[(size_t)node * NHT + c] = f2bf(v);
                }
            }
        }
    }
}

// ---------------- GCN gather (edge-split-2): out = dinv_i*(y_i + sum y_j)+b --
__global__ __launch_bounds__(256)
void gather_gcn_k(const int* __restrict__ row_start,
                  const int* __restrict__ csr,
                  const unsigned short* __restrict__ y,   // bf16, pre-scaled by dinv
                  const float* __restrict__ dinv,
                  const float* __restrict__ b_mu,
                  const float* __restrict__ b_ls,
                  float* __restrict__ out)
{
    int idx = blockIdx.x * 256 + threadIdx.x;    // NN*16 exact (3125 blocks)
    int i   = idx >> 4;
    int rem = idx & 15;
    int ch = rem >> 1, sub = rem & 1;
    int c8 = ch * 8;
    float a[8] = {0.f,0.f,0.f,0.f,0.f,0.f,0.f,0.f};
    if (sub == 0) {
        uint4 h = *(const uint4*)&y[(size_t)i * 64 + c8];
        a[0] = lof(h.x); a[1] = hif(h.x); a[2] = lof(h.y); a[3] = hif(h.y);
        a[4] = lof(h.z); a[5] = hif(h.z); a[6] = lof(h.w); a[7] = hif(h.w);
    }
    int e0 = row_start[i], e1 = row_start[i + 1];
    int e = e0 + sub;
    for (; e + 2 < e1; e += 4) {
        int s0 = csr[e], s1 = csr[e + 2];
        uint4 v0 = *(const uint4*)&y[(size_t)s0 * 64 + c8];
        uint4 v1 = *(const uint4*)&y[(size_t)s1 * 64 + c8];
        a[0] += lof(v0.x); a[1] += hif(v0.x); a[2] += lof(v0.y); a[3] += hif(v0.y);
        a[4] += lof(v0.z); a[5] += hif(v0.z); a[6] += lof(v0.w); a[7] += hif(v0.w);
        a[0] += lof(v1.x); a[1] += hif(v1.x); a[2] += lof(v1.y); a[3] += hif(v1.y);
        a[4] += lof(v1.z); a[5] += hif(v1.z); a[6] += lof(v1.w); a[7] += hif(v1.w);
    }
    if (e < e1) {
        int s = csr[e];
        uint4 v = *(const uint4*)&y[(size_t)s * 64 + c8];
        a[0] += lof(v.x); a[1] += hif(v.x); a[2] += lof(v.y); a[3] += hif(v.y);
        a[4] += lof(v.z); a[5] += hif(v.z); a[6] += lof(v.w); a[7] += hif(v.w);
    }
    #pragma unroll
    for (int q = 0; q < 8; ++q) a[q] += __shfl_xor(a[q], 1);
    if (sub) return;
    float di = dinv[i];
    const float* b;
    float* o;
    if (c8 < 32) { b = &b_mu[c8];      o = &out[(size_t)i * 32 + c8]; }
    else         { b = &b_ls[c8 - 32]; o = &out[(size_t)NN * 32 + (size_t)i * 32 + (c8 - 32)]; }
    float4 r0, r1;
    r0.x = di * a[0] + b[0]; r0.y = di * a[1] + b[1];
    r0.z = di * a[2] + b[2]; r0.w = di * a[3] + b[3];
    r1.x = di * a[4] + b[4]; r1.y = di * a[5] + b[5];
    r1.z = di * a[6] + b[6]; r1.w = di * a[7] + b[7];
    *(float4*)&o[0] = r0;
    *(float4*)&o[4] = r1;
}

extern "C" void kernel_launch(void* const* d_in, const int* in_sizes, int n_in,
                              void* d_out, int out_size, void* d_ws, size_t ws_size,
                              hipStream_t stream)
{
    (void)in_sizes; (void)n_in; (void)out_size; (void)ws_size;
    const float* x       = (const float*)d_in[0];
    const int*   ei      = (const int*)d_in[1];
    const int*   srcv    = ei;
    const int*   dstv    = ei + NE;
    const float* w1_rel  = (const float*)d_in[2];
    const float* w1_root = (const float*)d_in[3];
    const float* b1      = (const float*)d_in[4];
    const float* w2_rel  = (const float*)d_in[5];
    const float* w2_root = (const float*)d_in[6];
    const float* b2      = (const float*)d_in[7];
    const float* w_mu    = (const float*)d_in[8];
    const float* b_mu    = (const float*)d_in[9];
    const float* w_ls    = (const float*)d_in[10];
    const float* b_ls    = (const float*)d_in[11];
    float* out = (float*)d_out;

    char* ws = (char*)d_ws;
    unsigned short* t1    = (unsigned short*)(ws);              // 9.6MB  NN*96 bf16
    unsigned short* h1pre = (unsigned short*)(ws + 9600000);    // 9.6MB
    unsigned short* t2    = (unsigned short*)(ws + 19200000);   // 6.4MB  NN*64 bf16
    unsigned short* h2pre = (unsigned short*)(ws + 25600000);   // 6.4MB
    unsigned short* y     = (unsigned short*)(ws + 32000000);   // 6.4MB
    int* csr       = (int*)(ws + 38400000);                     // 2.4MB
    int* row_start = (int*)(ws + 40800000);                     // (NN+1)*4
    int* cursor    = (int*)(ws + 41000016);                     // NN*4
    float* dinv    = (float*)(ws + 41200016);                   // NN*4
    int* deg       = (int*)(ws + 41400016);                     // NN*4
    int* partial   = (int*)(ws + 41600016);                     // NB*4
    unsigned short* wt1 = (unsigned short*)(ws + 41700016);     // 192*128*2
    unsigned short* wt2 = (unsigned short*)(ws + 41749168);     // 128*96*2
    unsigned short* wt3 = (unsigned short*)(ws + 41773744);     // 64*64*2

    // ---- CSR build + norm + weight prep ----
    zero_wprep_k<<<NB, 256, 0, stream>>>(deg, w1_rel, w1_root, w2_rel, w2_root,
                                         w_mu, w_ls, wt1, wt2, wt3);
    count_deg_k<<<(NE + 255) / 256, 256, 0, stream>>>(dstv, deg);
    scan_reduce_k<<<NB, 256, 0, stream>>>(deg, partial);
    scan_final2_k<<<NB, 256, 0, stream>>>(deg, partial, row_start, cursor, dinv);
    fill_k<<<(NE + 255) / 256, 256, 0, stream>>>(srcv, dstv, cursor, csr);

    // ---- layer 1: t1 = x@w1_rel ; h1pre = x@w1_root + b1 ----
    gemm_mfma<128, 96, false, false><<<dim3(391, 2), 256, 0, stream>>>(
        x, wt1, b1, nullptr, t1, h1pre);

    // ---- layer 2 (fused): h1 = relu(h1pre + gather t1) in LDS;
    //      t2 = h1@w2_rel ; h2pre = h1@w2_root + b2 ----
    gather_gemm_k<96, 128, true, false><<<782, 512, 0, stream>>>(
        row_start, csr, t1, h1pre, wt2, b2, nullptr, t2, h2pre);

    // ---- layer 3 (fused): h2 = relu(h2pre + gather t2) in LDS;
    //      y = dinv * (h2 @ [w_mu | w_ls]) ----
    gather_gemm_k<64, 64, false, true><<<782, 512, 0, stream>>>(
        row_start, csr, t2, h2pre, wt3, nullptr, dinv, y, nullptr);

    // ---- GCN aggregate + bias -> out ----
    gather_gcn_k<<<(NN * 16) / 256, 256, 0, stream>>>(row_start, csr, y, dinv, b_mu, b_ls, out);
}